// Round 1
// baseline (1811.777 us; speedup 1.0000x reference)
//
#include <hip/hip_runtime.h>
#include <math.h>
#include <limits.h>

#define EPSB 1e-5f
#define R2C  0.09f

// ---- workspace offsets (floats). Total ~4.44M floats = ~17.8 MB ----
#define OFF_MASKF 0          // N*16
#define OFF_KERNF 1600000    // N*16
#define OFF_STATS 3200000    // 1024
#define OFF_VT    3201024    // 128*352
#define OFF_FEATW 3246080    // 128*36
#define OFF_MZ1   3250688    // 16384*36
#define OFF_MZ2   3840512    // 16384*36
#define OFF_INT   4430336    // 256 ints (topk 128 | cand_batch 128)

// =============================== zero stats ===============================
__global__ void k_zero(float* stats) {
    int t = threadIdx.x;
    if (t < 1024) stats[t] = 0.f;
}

// =============================== tower layer ==============================
// Y[n][j] = sum_k a[n][k] * W[k][j] (+bias), a = relu(bn(X)) if stats_in else X
// tile: 256 rows x COLS cols; thread = 4 rows x 8 cols
__global__ __launch_bounds__(256)
void k_tower(const float* __restrict__ X, const float* __restrict__ W,
             const float* __restrict__ bias, float* __restrict__ Y,
             const float* __restrict__ stats_in, float* __restrict__ stats_out,
             int N, int COLS) {
    __shared__ float As[32 * 256];
    __shared__ float Wsh[32 * 32];
    __shared__ float mrs[64];
    int tid = threadIdx.x;
    for (int t = tid; t < 32 * COLS; t += 256) Wsh[t] = W[t];
    if (stats_in && tid < 32) {
        float s = stats_in[tid], q = stats_in[32 + tid];
        float m = s / (float)N;
        float v = q / (float)N - m * m;
        mrs[tid] = m; mrs[32 + tid] = rsqrtf(v + EPSB);
    }
    __syncthreads();
    int row = blockIdx.x * 256 + tid;
    bool nrm = (stats_in != nullptr);
    if (row < N) {
        const float4* xr = (const float4*)(X + (size_t)row * 32);
#pragma unroll
        for (int q4 = 0; q4 < 8; q4++) {
            float4 v = xr[q4];
            float e[4] = {v.x, v.y, v.z, v.w};
#pragma unroll
            for (int u = 0; u < 4; u++) {
                float t = e[u];
                if (nrm) t = fmaxf((t - mrs[q4 * 4 + u]) * mrs[32 + q4 * 4 + u], 0.f);
                As[(q4 * 4 + u) * 256 + tid] = t;
            }
        }
    } else {
#pragma unroll
        for (int k = 0; k < 32; k++) As[k * 256 + tid] = 0.f;
    }
    __syncthreads();
    int rowg = tid & 63, colg = tid >> 6;
    int j0 = colg * 8;
    if (j0 >= COLS) return;
    float acc[4][8];
#pragma unroll
    for (int r = 0; r < 4; r++)
#pragma unroll
        for (int j = 0; j < 8; j++) acc[r][j] = 0.f;
#pragma unroll 4
    for (int k = 0; k < 32; k++) {
        float4 a4 = *(const float4*)&As[k * 256 + rowg * 4];
        float ar[4] = {a4.x, a4.y, a4.z, a4.w};
        float4 wa = *(const float4*)&Wsh[k * COLS + j0];
        float4 wb = *(const float4*)&Wsh[k * COLS + j0 + 4];
        float wr[8] = {wa.x, wa.y, wa.z, wa.w, wb.x, wb.y, wb.z, wb.w};
#pragma unroll
        for (int r = 0; r < 4; r++)
#pragma unroll
            for (int j = 0; j < 8; j++) acc[r][j] += ar[r] * wr[j];
    }
    if (bias) {
#pragma unroll
        for (int j = 0; j < 8; j++) {
            float bj = bias[j0 + j];
#pragma unroll
            for (int r = 0; r < 4; r++) acc[r][j] += bj;
        }
    }
    int rbase = blockIdx.x * 256 + rowg * 4;
#pragma unroll
    for (int r = 0; r < 4; r++) {
        int rr = rbase + r;
        if (rr < N) {
            float4 o0 = {acc[r][0], acc[r][1], acc[r][2], acc[r][3]};
            float4 o1 = {acc[r][4], acc[r][5], acc[r][6], acc[r][7]};
            *(float4*)(Y + (size_t)rr * COLS + j0) = o0;
            *(float4*)(Y + (size_t)rr * COLS + j0 + 4) = o1;
        }
    }
    if (stats_out) {
#pragma unroll
        for (int j = 0; j < 8; j++) {
            float s = acc[0][j] + acc[1][j] + acc[2][j] + acc[3][j];
            float q = acc[0][j] * acc[0][j] + acc[1][j] * acc[1][j] +
                      acc[2][j] * acc[2][j] + acc[3][j] * acc[3][j];
#pragma unroll
            for (int off = 32; off > 0; off >>= 1) {
                s += __shfl_down(s, off);
                q += __shfl_down(q, off);
            }
            if ((tid & 63) == 0) {
                atomicAdd(&stats_out[j0 + j], s);
                atomicAdd(&stats_out[32 + j0 + j], q);
            }
        }
    }
}

// ================================= NMS ====================================
#define NBINS 2048
#define NCAP  2176
#define NM    2048
__global__ __launch_bounds__(1024)
void k_nms(const float* __restrict__ heat, const float* __restrict__ coords,
           const int* __restrict__ bidx, int N, int* __restrict__ topk) {
    __shared__ float ch[NCAP], cxs[NCAP], cys[NCAP], czs[NCAP];
    __shared__ int   cid[NCAP];
    __shared__ int   hist[NBINS];
    __shared__ float rv[16]; __shared__ int ri[16], rp[16];
    __shared__ int   sh_s, sh_e, sh_T, sh_cnt, sh_pos;
    __shared__ float sh_val;
    __shared__ float fbx[32], fby[32], fbz[32];
    int b = blockIdx.x, tid = threadIdx.x;
    if (tid == 0) {
        int lo = 0, hi = N;
        while (lo < hi) { int m = (lo + hi) >> 1; if (bidx[m] < b) lo = m + 1; else hi = m; }
        sh_s = lo;
        lo = 0; hi = N;
        while (lo < hi) { int m = (lo + hi) >> 1; if (bidx[m] < b + 1) lo = m + 1; else hi = m; }
        sh_e = lo;
    }
    __syncthreads();
    int s = sh_s, e = sh_e, nb = e - s;
    if (nb <= 0) {
        for (int t = tid; t < 32; t += 1024) topk[b * 32 + t] = 0;
        return;
    }
    for (int i = tid; i < NBINS; i += 1024) hist[i] = 0;
    __syncthreads();
    for (int n = s + tid; n < e; n += 1024) {
        float h = heat[n];
        int bin = (int)(h * (float)NBINS);
        bin = min(max(bin, 0), NBINS - 1);
        atomicAdd(&hist[bin], 1);
    }
    __syncthreads();
    // suffix-sum scan (Hillis-Steele), 2 bins / thread
    for (int off = 1; off < NBINS; off <<= 1) {
        int i0 = tid, i1 = tid + 1024;
        int v0 = hist[i0] + ((i0 + off < NBINS) ? hist[i0 + off] : 0);
        int v1 = hist[i1] + ((i1 + off < NBINS) ? hist[i1 + off] : 0);
        __syncthreads();
        hist[i0] = v0; hist[i1] = v1;
        __syncthreads();
    }
    int Meff = min(NM, nb);
    {
        int i0 = tid, i1 = tid + 1024;
        if (hist[i0] >= Meff && (i0 == NBINS - 1 || hist[i0 + 1] < Meff)) sh_T = i0;
        if (hist[i1] >= Meff && (i1 == NBINS - 1 || hist[i1 + 1] < Meff)) sh_T = i1;
    }
    if (tid == 0) sh_cnt = 0;
    __syncthreads();
    int T = sh_T;
    float thr = (float)T * (1.0f / (float)NBINS);   // exact: T*2^-11
    for (int n = s + tid; n < e; n += 1024) {
        float h = heat[n];
        int bin = (int)(h * (float)NBINS);
        bin = min(max(bin, 0), NBINS - 1);
        if (bin >= T) {
            int p = atomicAdd(&sh_cnt, 1);
            if (p < NCAP) {
                ch[p] = h; cid[p] = n;
                cxs[p] = coords[(size_t)n * 3 + 0];
                cys[p] = coords[(size_t)n * 3 + 1];
                czs[p] = coords[(size_t)n * 3 + 2];
            }
        }
    }
    __syncthreads();
    int C = min(sh_cnt, NCAP);
    bool overflow = (sh_cnt > NCAP);
    for (int t = 0; t < 32; t++) {
        float bv = -INFINITY; int bo = INT_MAX; int bp = -1;
        for (int i = tid; i < C; i += 1024) {
            float v = ch[i]; int oi = cid[i];
            if (v > bv || (v == bv && oi < bo)) { bv = v; bo = oi; bp = i; }
        }
#pragma unroll
        for (int off = 32; off > 0; off >>= 1) {
            float ov = __shfl_down(bv, off);
            int ooi = __shfl_down(bo, off);
            int op  = __shfl_down(bp, off);
            if (ov > bv || (ov == bv && ooi < bo)) { bv = ov; bo = ooi; bp = op; }
        }
        if ((tid & 63) == 0) { int w = tid >> 6; rv[w] = bv; ri[w] = bo; rp[w] = bp; }
        __syncthreads();
        if (tid == 0) {
            bv = rv[0]; bo = ri[0]; bp = rp[0];
            for (int w = 1; w < 16; w++)
                if (rv[w] > bv || (rv[w] == bv && ri[w] < bo)) { bv = rv[w]; bo = ri[w]; bp = rp[w]; }
            sh_pos = bp; sh_val = bv;
            topk[b * 32 + t] = cid[bp];
        }
        __syncthreads();
        int sp = sh_pos;
        float sx = cxs[sp], sy = cys[sp], sz = czs[sp];
        for (int i = tid; i < C; i += 1024) {
            float dx = cxs[i] - sx, dy = cys[i] - sy, dz = czs[i] - sz;
            float d2 = dx * dx + dy * dy + dz * dz;
            if (d2 < R2C) ch[i] = -INFINITY;
        }
        __syncthreads();
    }
    // soundness: selections are non-increasing; all excluded points are < thr.
    bool sound = (!overflow) && (sh_val >= thr);
    if (!sound) {
        // brute-force exact fallback (essentially never taken)
        for (int t = 0; t < 32; t++) {
            float bv = -INFINITY; int bo = INT_MAX;
            for (int n = s + tid; n < e; n += 1024) {
                float x = coords[(size_t)n * 3], y = coords[(size_t)n * 3 + 1], z = coords[(size_t)n * 3 + 2];
                bool sup = false;
                for (int u = 0; u < t; u++) {
                    float dx = x - fbx[u], dy = y - fby[u], dz = z - fbz[u];
                    if (dx * dx + dy * dy + dz * dz < R2C) { sup = true; break; }
                }
                if (!sup) {
                    float h = heat[n];
                    if (h > bv || (h == bv && n < bo)) { bv = h; bo = n; }
                }
            }
#pragma unroll
            for (int off = 32; off > 0; off >>= 1) {
                float ov = __shfl_down(bv, off); int oo = __shfl_down(bo, off);
                if (ov > bv || (ov == bv && oo < bo)) { bv = ov; bo = oo; }
            }
            if ((tid & 63) == 0) { int w = tid >> 6; rv[w] = bv; ri[w] = bo; }
            __syncthreads();
            if (tid == 0) {
                bv = rv[0]; bo = ri[0];
                for (int w = 1; w < 16; w++)
                    if (rv[w] > bv || (rv[w] == bv && ri[w] < bo)) { bv = rv[w]; bo = ri[w]; }
                topk[b * 32 + t] = bo;
                fbx[t] = coords[(size_t)bo * 3];
                fby[t] = coords[(size_t)bo * 3 + 1];
                fbz[t] = coords[(size_t)bo * 3 + 2];
            }
            __syncthreads();
        }
    }
}

// ============================ instance prep ===============================
// weights row = ck @ Wwg + bwg; build folded V^T [j=0..15][k=0..19] (+w2,b2), feat row
__global__ __launch_bounds__(384)
void k_prep(const int* __restrict__ topk, const float* __restrict__ coords,
            const int* __restrict__ bidx, const float* __restrict__ maskf,
            const float* __restrict__ kernf, const float* __restrict__ Wwg,
            const float* __restrict__ bwg, float* __restrict__ Vt,
            float* __restrict__ featw, int* __restrict__ cand_batch) {
    __shared__ float ck[16], cm[16], ctr[3], wrow[337];
    int i = blockIdx.x, tid = threadIdx.x;
    int idx = topk[i];
    if (tid < 16) { ck[tid] = kernf[(size_t)idx * 16 + tid]; cm[tid] = maskf[(size_t)idx * 16 + tid]; }
    else if (tid < 19) ctr[tid - 16] = coords[(size_t)idx * 3 + (tid - 16)];
    else if (tid == 19) cand_batch[i] = bidx[idx];
    __syncthreads();
    for (int c = tid; c < 337; c += 384) {
        float acc = bwg[c];
#pragma unroll
        for (int m = 0; m < 16; m++) acc += ck[m] * Wwg[m * 337 + c];
        wrow[c] = acc;
    }
    __syncthreads();
    for (int t = tid; t < 352; t += 384) {
        float v;
        if (t < 320) {
            int j = t / 20, k = t - j * 20;
            if (k < 19) v = wrow[k * 16 + j];
            else {
                v = wrow[304 + j];
#pragma unroll
                for (int p = 0; p < 3; p++) v -= ctr[p] * wrow[(16 + p) * 16 + j];
            }
        } else if (t < 336) v = wrow[320 + (t - 320)];
        else if (t == 336) v = wrow[336];
        else v = 0.f;
        Vt[(size_t)i * 352 + t] = v;
    }
    for (int t = tid; t < 36; t += 384)
        featw[i * 36 + t] = (t < 16) ? ck[t] : (t < 32) ? cm[t - 16] : (t < 35) ? ctr[t - 32] : 0.f;
}

// ============================== mask heads ================================
#define MASK_H(p, ACC) { \
    float h = v4.w; \
    h += f[p][0]*v0.x + f[p][1]*v0.y + f[p][2]*v0.z + f[p][3]*v0.w; \
    h += f[p][4]*v1.x + f[p][5]*v1.y + f[p][6]*v1.z + f[p][7]*v1.w; \
    h += f[p][8]*v2.x + f[p][9]*v2.y + f[p][10]*v2.z + f[p][11]*v2.w; \
    h += f[p][12]*v3.x + f[p][13]*v3.y + f[p][14]*v3.z + f[p][15]*v3.w; \
    h += cx[p]*v4.x + cy[p]*v4.y + cz[p]*v4.z; \
    ACC += fmaxf(h, 0.f) * w2j; }

__global__ __launch_bounds__(256)
void k_mask(const float* __restrict__ maskf, const float* __restrict__ coords,
            const float* __restrict__ Vt, float* __restrict__ out,
            int N, int ostride) {
    __shared__ float Vs[352];
    int tid = threadIdx.x;
    int nb0 = blockIdx.x * 1024;
    float f[4][16], cx[4], cy[4], cz[4];
    bool val[4];
#pragma unroll
    for (int p = 0; p < 4; p++) {
        int n = nb0 + p * 256 + tid;
        val[p] = (n < N);
        if (val[p]) {
            const float4* fr = (const float4*)(maskf + (size_t)n * 16);
            float4 a = fr[0], b = fr[1], c = fr[2], d = fr[3];
            f[p][0]=a.x; f[p][1]=a.y; f[p][2]=a.z; f[p][3]=a.w;
            f[p][4]=b.x; f[p][5]=b.y; f[p][6]=b.z; f[p][7]=b.w;
            f[p][8]=c.x; f[p][9]=c.y; f[p][10]=c.z; f[p][11]=c.w;
            f[p][12]=d.x; f[p][13]=d.y; f[p][14]=d.z; f[p][15]=d.w;
            cx[p]=coords[(size_t)n*3]; cy[p]=coords[(size_t)n*3+1]; cz[p]=coords[(size_t)n*3+2];
        } else {
#pragma unroll
            for (int k = 0; k < 16; k++) f[p][k] = 0.f;
            cx[p] = cy[p] = cz[p] = 0.f;
        }
    }
    int ibase = blockIdx.y * 32;
    for (int ii = 0; ii < 32; ii++) {
        int i = ibase + ii;
        __syncthreads();
        for (int t = tid; t < 352; t += 256) Vs[t] = Vt[(size_t)i * 352 + t];
        __syncthreads();
        float acc0 = 0.f, acc1 = 0.f, acc2 = 0.f, acc3 = 0.f;
#pragma unroll 4
        for (int j = 0; j < 16; j++) {
            const float* vj = &Vs[j * 20];
            float4 v0 = *(const float4*)(vj);
            float4 v1 = *(const float4*)(vj + 4);
            float4 v2 = *(const float4*)(vj + 8);
            float4 v3 = *(const float4*)(vj + 12);
            float4 v4 = *(const float4*)(vj + 16);
            float w2j = Vs[320 + j];
            MASK_H(0, acc0) MASK_H(1, acc1) MASK_H(2, acc2) MASK_H(3, acc3)
        }
        float b2 = Vs[336];
        size_t rb = (size_t)i * ostride + nb0 + tid;
        if (val[0]) out[rb]         = 1.f / (1.f + __expf(-(acc0 + b2)));
        if (val[1]) out[rb + 256]   = 1.f / (1.f + __expf(-(acc1 + b2)));
        if (val[2]) out[rb + 512]   = 1.f / (1.f + __expf(-(acc2 + b2)));
        if (val[3]) out[rb + 768]   = 1.f / (1.f + __expf(-(acc3 + b2)));
    }
}

// ============================== merge tower ===============================
__global__ __launch_bounds__(128)
void k_merge1(const float* __restrict__ featw, const float* __restrict__ Wg,
              float* __restrict__ Z, float* __restrict__ stats_out) {
    __shared__ float F[128 * 36];
    int tid = threadIdx.x;
    for (int t = tid; t < 128 * 36; t += 128) F[t] = featw[t];
    __syncthreads();
    int id = blockIdx.x * 128 + tid;
    int a = id >> 7, b = id & 127;
    float d[35];
#pragma unroll
    for (int k = 0; k < 35; k++) d[k] = fmaxf(fabsf(F[a * 36 + k] - F[b * 36 + k]), 1e-6f);
    float z[35];
#pragma unroll
    for (int j = 0; j < 35; j++) z[j] = 0.f;
    for (int k = 0; k < 35; k++) {
        float dk = d[k];
        const float* wr = Wg + k * 35;
#pragma unroll
        for (int j = 0; j < 35; j++) z[j] += dk * wr[j];
    }
#pragma unroll
    for (int j = 0; j < 35; j++) {
        float s = z[j], q = z[j] * z[j];
#pragma unroll
        for (int off = 32; off > 0; off >>= 1) { s += __shfl_down(s, off); q += __shfl_down(q, off); }
        if ((tid & 63) == 0) { atomicAdd(&stats_out[j], s); atomicAdd(&stats_out[35 + j], q); }
    }
    float* zr = Z + (size_t)id * 36;
#pragma unroll
    for (int j = 0; j < 35; j++) zr[j] = z[j];
}

__global__ __launch_bounds__(128)
void k_merge_mid(const float* __restrict__ Zin, const float* __restrict__ Wg,
                 float* __restrict__ Zout, const float* __restrict__ stats_in,
                 float* __restrict__ stats_out) {
    __shared__ float nrm[70];
    int tid = threadIdx.x;
    if (tid < 35) {
        float s = stats_in[tid], q = stats_in[35 + tid];
        float m = s * (1.f / 16384.f);
        float v = q * (1.f / 16384.f) - m * m;
        nrm[tid] = m; nrm[35 + tid] = rsqrtf(v + EPSB);
    }
    __syncthreads();
    int id = blockIdx.x * 128 + tid;
    const float* zi = Zin + (size_t)id * 36;
    float x[35];
#pragma unroll
    for (int k = 0; k < 35; k++) x[k] = fmaxf((zi[k] - nrm[k]) * nrm[35 + k], 0.f);
    float z[35];
#pragma unroll
    for (int j = 0; j < 35; j++) z[j] = 0.f;
    for (int k = 0; k < 35; k++) {
        float dk = x[k];
        const float* wr = Wg + k * 35;
#pragma unroll
        for (int j = 0; j < 35; j++) z[j] += dk * wr[j];
    }
#pragma unroll
    for (int j = 0; j < 35; j++) {
        float s = z[j], q = z[j] * z[j];
#pragma unroll
        for (int off = 32; off > 0; off >>= 1) { s += __shfl_down(s, off); q += __shfl_down(q, off); }
        if ((tid & 63) == 0) { atomicAdd(&stats_out[j], s); atomicAdd(&stats_out[35 + j], q); }
    }
    float* zr = Zout + (size_t)id * 36;
#pragma unroll
    for (int j = 0; j < 35; j++) zr[j] = z[j];
}

__global__ __launch_bounds__(128)
void k_merge_out(const float* __restrict__ Zin, const float* __restrict__ Wout,
                 const float* __restrict__ bout, const float* __restrict__ stats_in,
                 const int* __restrict__ cand_batch, float* __restrict__ out,
                 int N, int ostride) {
    __shared__ float nrm[70];
    __shared__ int cb[128];
    int tid = threadIdx.x;
    if (tid < 35) {
        float s = stats_in[tid], q = stats_in[35 + tid];
        float m = s * (1.f / 16384.f);
        float v = q * (1.f / 16384.f) - m * m;
        nrm[tid] = m; nrm[35 + tid] = rsqrtf(v + EPSB);
    }
    cb[tid] = cand_batch[tid];
    __syncthreads();
    int id = blockIdx.x * 128 + tid;
    int a = id >> 7, b = id & 127;
    const float* zi = Zin + (size_t)id * 36;
    float s = bout[0];
    for (int k = 0; k < 35; k++)
        s += fmaxf((zi[k] - nrm[k]) * nrm[35 + k], 0.f) * Wout[k];
    float v = 1.f / (1.f + __expf(-s));
    if (cb[a] != cb[b]) v = 0.f;
    out[(size_t)a * ostride + N + b] = v;
}

// =============================== launcher =================================
extern "C" void kernel_launch(void* const* d_in, const int* in_sizes, int n_in,
                              void* d_out, int out_size, void* d_ws, size_t ws_size,
                              hipStream_t stream) {
    const float* of     = (const float*)d_in[0];
    const float* coords = (const float*)d_in[1];
    const float* heat   = (const float*)d_in[2];
    const int*   bidx   = (const int*)d_in[3];
    const float* Wm     = (const float*)d_in[4];
    const float* Wm_out = (const float*)d_in[5];
    const float* bm_out = (const float*)d_in[6];
    const float* Wk     = (const float*)d_in[7];
    const float* Wk_out = (const float*)d_in[8];
    const float* bk_out = (const float*)d_in[9];
    const float* Wg     = (const float*)d_in[10];
    const float* Wg_out = (const float*)d_in[11];
    const float* bg_out = (const float*)d_in[12];
    const float* Wwg    = (const float*)d_in[13];
    const float* bwg    = (const float*)d_in[14];
    float* out = (float*)d_out;
    float* ws  = (float*)d_ws;

    int N = in_sizes[0] / 32;          // 100000
    int ostride = N + 128;             // 100128

    float* maskf = ws + OFF_MASKF;
    float* kernf = ws + OFF_KERNF;
    float* stats = ws + OFF_STATS;
    float* Vt    = ws + OFF_VT;
    float* featw = ws + OFF_FEATW;
    float* mz1   = ws + OFF_MZ1;
    float* mz2   = ws + OFF_MZ2;
    int*   topk  = (int*)(ws + OFF_INT);
    int*   cand_batch = topk + 128;

    // tower ping-pong buffers live inside d_out (overwritten before epilogue writes)
    float* bufA = out;
    float* bufB = out + (size_t)N * 32;

    dim3 tg((N + 255) / 256);

    k_zero<<<1, 1024, 0, stream>>>(stats);
    k_nms<<<4, 1024, 0, stream>>>(heat, coords, bidx, N, topk);
    // mask tower
    k_tower<<<tg, 256, 0, stream>>>(of,   Wm,        nullptr, bufA,  nullptr,   stats + 0,   N, 32);
    k_tower<<<tg, 256, 0, stream>>>(bufA, Wm + 1024, nullptr, bufB,  stats + 0,   stats + 64,  N, 32);
    k_tower<<<tg, 256, 0, stream>>>(bufB, Wm + 2048, nullptr, bufA,  stats + 64,  stats + 128, N, 32);
    k_tower<<<tg, 256, 0, stream>>>(bufA, Wm_out,    bm_out,  maskf, stats + 128, nullptr,   N, 16);
    // kernel tower
    k_tower<<<tg, 256, 0, stream>>>(of,   Wk,        nullptr, bufA,  nullptr,   stats + 192, N, 32);
    k_tower<<<tg, 256, 0, stream>>>(bufA, Wk + 1024, nullptr, bufB,  stats + 192, stats + 256, N, 32);
    k_tower<<<tg, 256, 0, stream>>>(bufB, Wk + 2048, nullptr, bufA,  stats + 256, stats + 320, N, 32);
    k_tower<<<tg, 256, 0, stream>>>(bufA, Wk_out,    bk_out,  kernf, stats + 320, nullptr,   N, 16);

    k_prep<<<128, 384, 0, stream>>>(topk, coords, bidx, maskf, kernf, Wwg, bwg,
                                    Vt, featw, cand_batch);
    k_mask<<<dim3((N + 1023) / 1024, 4), 256, 0, stream>>>(maskf, coords, Vt, out, N, ostride);

    k_merge1<<<128, 128, 0, stream>>>(featw, Wg, mz1, stats + 384);
    k_merge_mid<<<128, 128, 0, stream>>>(mz1, Wg + 1225, mz2, stats + 384, stats + 454);
    k_merge_mid<<<128, 128, 0, stream>>>(mz2, Wg + 2450, mz1, stats + 454, stats + 524);
    k_merge_out<<<128, 128, 0, stream>>>(mz1, Wg_out, bg_out, stats + 524, cand_batch,
                                         out, N, ostride);
}

// Round 2
// 935.488 us; speedup vs baseline: 1.9367x; 1.9367x over previous
//
#include <hip/hip_runtime.h>
#include <math.h>
#include <limits.h>

#define EPSB 1e-5f
#define R2C  0.09f

// ---- workspace offsets (floats). Total ~4.44M floats = ~17.8 MB ----
#define OFF_MASKF 0          // N*16
#define OFF_KERNF 1600000    // N*16
#define OFF_STATS 3200000    // 1024
#define OFF_VT    3201024    // 128*352
#define OFF_FEATW 3246080    // 128*36
#define OFF_MZ1   3250688    // 16384*36
#define OFF_MZ2   3840512    // 16384*36
#define OFF_INT   4430336    // 256 ints (topk 128 | cand_batch 128)

// =============================== zero stats ===============================
__global__ void k_zero(float* stats) {
    int t = threadIdx.x;
    if (t < 1024) stats[t] = 0.f;
}

// =============================== tower layer ==============================
// Y[n][j] = sum_k a[n][k] * W[k][j] (+bias), a = relu(bn(X)) if stats_in else X
// Coalesced stage-in -> LDS [row][k] (stride 33, conflict-free), 1 row/thread
// compute with wave-uniform (scalar) W loads, LDS-staged coalesced stage-out.
template <int COLS>
__global__ __launch_bounds__(256)
void k_tower(const float* __restrict__ X, const float* __restrict__ W,
             const float* __restrict__ bias, float* __restrict__ Y,
             const float* __restrict__ stats_in, float* __restrict__ stats_out,
             int N) {
    __shared__ float As[256 * 33];
    __shared__ float mrs[64];
    __shared__ float red[256];
    int tid = threadIdx.x;
    if (stats_in && tid < 32) {
        float s = stats_in[tid], q = stats_in[32 + tid];
        float m = s / (float)N;
        float v = q / (float)N - m * m;
        mrs[tid] = m; mrs[32 + tid] = rsqrtf(v + EPSB);
    }
    __syncthreads();
    int rbase = blockIdx.x * 256;
    int rmax = N - rbase; if (rmax > 256) rmax = 256;
    bool nrm = (stats_in != nullptr);
    // ---- coalesced stage-in (+BN/ReLU) ----
    const float4* Xv = (const float4*)(X + (size_t)rbase * 32);
    for (int f = tid; f < 2048; f += 256) {
        int r = f >> 3, c0 = (f & 7) * 4;
        float4 v = make_float4(0.f, 0.f, 0.f, 0.f);
        if (r < rmax) v = Xv[f];
        float e[4] = {v.x, v.y, v.z, v.w};
        float* dst = &As[r * 33 + c0];
#pragma unroll
        for (int u = 0; u < 4; u++) {
            float t = e[u];
            if (nrm) t = fmaxf((t - mrs[c0 + u]) * mrs[32 + c0 + u], 0.f);
            dst[u] = t;
        }
    }
    __syncthreads();
    // ---- compute: one row per thread ----
    float acc[COLS];
#pragma unroll
    for (int j = 0; j < COLS; j++) acc[j] = 0.f;
    if (bias) {
#pragma unroll
        for (int j = 0; j < COLS; j++) acc[j] = bias[j];
    }
#pragma unroll 4
    for (int k = 0; k < 32; k++) {
        float a = As[tid * 33 + k];
        const float* wr = W + k * COLS;   // wave-uniform -> scalar loads
#pragma unroll
        for (int j = 0; j < COLS; j++) acc[j] = fmaf(a, wr[j], acc[j]);
    }
    // ---- BN stats (sum, sumsq per column) ----
    if (stats_out) {
        int wv = tid >> 6;
#pragma unroll
        for (int j = 0; j < 32; j++) {
            float s = acc[j], q = acc[j] * acc[j];
#pragma unroll
            for (int off = 32; off > 0; off >>= 1) {
                s += __shfl_down(s, off);
                q += __shfl_down(q, off);
            }
            if ((tid & 63) == 0) { red[wv * 64 + j] = s; red[wv * 64 + 32 + j] = q; }
        }
        __syncthreads();
        if (tid < 64) {
            float s = red[tid] + red[64 + tid] + red[128 + tid] + red[192 + tid];
            atomicAdd(&stats_out[tid], s);
        }
    }
    // ---- stage-out through LDS, coalesced global write ----
    __syncthreads();   // everyone done reading As rows
#pragma unroll
    for (int j = 0; j < COLS; j++) As[tid * 33 + j] = acc[j];
    __syncthreads();
    constexpr int C4 = COLS / 4;
    for (int f = tid; f < 256 * C4; f += 256) {
        int r = f / C4, c0 = (f % C4) * 4;
        if (r < rmax) {
            const float* sp = &As[r * 33 + c0];
            float4 o = {sp[0], sp[1], sp[2], sp[3]};
            *(float4*)(Y + (size_t)(rbase + r) * COLS + c0) = o;
        }
    }
}

// ================================= NMS ====================================
#define NBINS 2048
#define NCAP  2176
#define NM    2048
__global__ __launch_bounds__(1024)
void k_nms(const float* __restrict__ heat, const float* __restrict__ coords,
           const int* __restrict__ bidx, int N, int* __restrict__ topk) {
    __shared__ float ch[NCAP], cxs[NCAP], cys[NCAP], czs[NCAP];
    __shared__ int   cid[NCAP];
    __shared__ int   hist[NBINS];
    __shared__ float rv[16]; __shared__ int ri[16], rp[16];
    __shared__ int   sh_s, sh_e, sh_T, sh_cnt, sh_pos;
    __shared__ float sh_val;
    __shared__ float fbx[32], fby[32], fbz[32];
    int b = blockIdx.x, tid = threadIdx.x;
    if (tid == 0) {
        int lo = 0, hi = N;
        while (lo < hi) { int m = (lo + hi) >> 1; if (bidx[m] < b) lo = m + 1; else hi = m; }
        sh_s = lo;
        lo = 0; hi = N;
        while (lo < hi) { int m = (lo + hi) >> 1; if (bidx[m] < b + 1) lo = m + 1; else hi = m; }
        sh_e = lo;
    }
    __syncthreads();
    int s = sh_s, e = sh_e, nb = e - s;
    if (nb <= 0) {
        for (int t = tid; t < 32; t += 1024) topk[b * 32 + t] = 0;
        return;
    }
    for (int i = tid; i < NBINS; i += 1024) hist[i] = 0;
    __syncthreads();
    for (int n = s + tid; n < e; n += 1024) {
        float h = heat[n];
        int bin = (int)(h * (float)NBINS);
        bin = min(max(bin, 0), NBINS - 1);
        atomicAdd(&hist[bin], 1);
    }
    __syncthreads();
    // suffix-sum scan (Hillis-Steele), 2 bins / thread
    for (int off = 1; off < NBINS; off <<= 1) {
        int i0 = tid, i1 = tid + 1024;
        int v0 = hist[i0] + ((i0 + off < NBINS) ? hist[i0 + off] : 0);
        int v1 = hist[i1] + ((i1 + off < NBINS) ? hist[i1 + off] : 0);
        __syncthreads();
        hist[i0] = v0; hist[i1] = v1;
        __syncthreads();
    }
    int Meff = min(NM, nb);
    {
        int i0 = tid, i1 = tid + 1024;
        if (hist[i0] >= Meff && (i0 == NBINS - 1 || hist[i0 + 1] < Meff)) sh_T = i0;
        if (hist[i1] >= Meff && (i1 == NBINS - 1 || hist[i1 + 1] < Meff)) sh_T = i1;
    }
    if (tid == 0) sh_cnt = 0;
    __syncthreads();
    int T = sh_T;
    float thr = (float)T * (1.0f / (float)NBINS);   // exact: T*2^-11
    for (int n = s + tid; n < e; n += 1024) {
        float h = heat[n];
        int bin = (int)(h * (float)NBINS);
        bin = min(max(bin, 0), NBINS - 1);
        if (bin >= T) {
            int p = atomicAdd(&sh_cnt, 1);
            if (p < NCAP) {
                ch[p] = h; cid[p] = n;
                cxs[p] = coords[(size_t)n * 3 + 0];
                cys[p] = coords[(size_t)n * 3 + 1];
                czs[p] = coords[(size_t)n * 3 + 2];
            }
        }
    }
    __syncthreads();
    int C = min(sh_cnt, NCAP);
    bool overflow = (sh_cnt > NCAP);
    for (int t = 0; t < 32; t++) {
        float bv = -INFINITY; int bo = INT_MAX; int bp = -1;
        for (int i = tid; i < C; i += 1024) {
            float v = ch[i]; int oi = cid[i];
            if (v > bv || (v == bv && oi < bo)) { bv = v; bo = oi; bp = i; }
        }
#pragma unroll
        for (int off = 32; off > 0; off >>= 1) {
            float ov = __shfl_down(bv, off);
            int ooi = __shfl_down(bo, off);
            int op  = __shfl_down(bp, off);
            if (ov > bv || (ov == bv && ooi < bo)) { bv = ov; bo = ooi; bp = op; }
        }
        if ((tid & 63) == 0) { int w = tid >> 6; rv[w] = bv; ri[w] = bo; rp[w] = bp; }
        __syncthreads();
        if (tid == 0) {
            bv = rv[0]; bo = ri[0]; bp = rp[0];
            for (int w = 1; w < 16; w++)
                if (rv[w] > bv || (rv[w] == bv && ri[w] < bo)) { bv = rv[w]; bo = ri[w]; bp = rp[w]; }
            sh_pos = bp; sh_val = bv;
            topk[b * 32 + t] = cid[bp];
        }
        __syncthreads();
        int sp = sh_pos;
        float sx = cxs[sp], sy = cys[sp], sz = czs[sp];
        for (int i = tid; i < C; i += 1024) {
            float dx = cxs[i] - sx, dy = cys[i] - sy, dz = czs[i] - sz;
            float d2 = dx * dx + dy * dy + dz * dz;
            if (d2 < R2C) ch[i] = -INFINITY;
        }
        __syncthreads();
    }
    // soundness: selections are non-increasing; all excluded points are < thr.
    bool sound = (!overflow) && (sh_val >= thr);
    if (!sound) {
        // brute-force exact fallback (essentially never taken)
        for (int t = 0; t < 32; t++) {
            float bv = -INFINITY; int bo = INT_MAX;
            for (int n = s + tid; n < e; n += 1024) {
                float x = coords[(size_t)n * 3], y = coords[(size_t)n * 3 + 1], z = coords[(size_t)n * 3 + 2];
                bool sup = false;
                for (int u = 0; u < t; u++) {
                    float dx = x - fbx[u], dy = y - fby[u], dz = z - fbz[u];
                    if (dx * dx + dy * dy + dz * dz < R2C) { sup = true; break; }
                }
                if (!sup) {
                    float h = heat[n];
                    if (h > bv || (h == bv && n < bo)) { bv = h; bo = n; }
                }
            }
#pragma unroll
            for (int off = 32; off > 0; off >>= 1) {
                float ov = __shfl_down(bv, off); int oo = __shfl_down(bo, off);
                if (ov > bv || (ov == bv && oo < bo)) { bv = ov; bo = oo; }
            }
            if ((tid & 63) == 0) { int w = tid >> 6; rv[w] = bv; ri[w] = bo; }
            __syncthreads();
            if (tid == 0) {
                bv = rv[0]; bo = ri[0];
                for (int w = 1; w < 16; w++)
                    if (rv[w] > bv || (rv[w] == bv && ri[w] < bo)) { bv = rv[w]; bo = ri[w]; }
                topk[b * 32 + t] = bo;
                fbx[t] = coords[(size_t)bo * 3];
                fby[t] = coords[(size_t)bo * 3 + 1];
                fbz[t] = coords[(size_t)bo * 3 + 2];
            }
            __syncthreads();
        }
    }
}

// ============================ instance prep ===============================
__global__ __launch_bounds__(384)
void k_prep(const int* __restrict__ topk, const float* __restrict__ coords,
            const int* __restrict__ bidx, const float* __restrict__ maskf,
            const float* __restrict__ kernf, const float* __restrict__ Wwg,
            const float* __restrict__ bwg, float* __restrict__ Vt,
            float* __restrict__ featw, int* __restrict__ cand_batch) {
    __shared__ float ck[16], cm[16], ctr[3], wrow[337];
    int i = blockIdx.x, tid = threadIdx.x;
    int idx = topk[i];
    if (tid < 16) { ck[tid] = kernf[(size_t)idx * 16 + tid]; cm[tid] = maskf[(size_t)idx * 16 + tid]; }
    else if (tid < 19) ctr[tid - 16] = coords[(size_t)idx * 3 + (tid - 16)];
    else if (tid == 19) cand_batch[i] = bidx[idx];
    __syncthreads();
    for (int c = tid; c < 337; c += 384) {
        float acc = bwg[c];
#pragma unroll
        for (int m = 0; m < 16; m++) acc += ck[m] * Wwg[m * 337 + c];
        wrow[c] = acc;
    }
    __syncthreads();
    for (int t = tid; t < 352; t += 384) {
        float v;
        if (t < 320) {
            int j = t / 20, k = t - j * 20;
            if (k < 19) v = wrow[k * 16 + j];
            else {
                v = wrow[304 + j];
#pragma unroll
                for (int p = 0; p < 3; p++) v -= ctr[p] * wrow[(16 + p) * 16 + j];
            }
        } else if (t < 336) v = wrow[320 + (t - 320)];
        else if (t == 336) v = wrow[336];
        else v = 0.f;
        Vt[(size_t)i * 352 + t] = v;
    }
    for (int t = tid; t < 36; t += 384)
        featw[i * 36 + t] = (t < 16) ? ck[t] : (t < 32) ? cm[t - 16] : (t < 35) ? ctr[t - 32] : 0.f;
}

// ============================== mask heads ================================
#define MASK_H(p, ACC) { \
    float h = v4.w; \
    h += f[p][0]*v0.x + f[p][1]*v0.y + f[p][2]*v0.z + f[p][3]*v0.w; \
    h += f[p][4]*v1.x + f[p][5]*v1.y + f[p][6]*v1.z + f[p][7]*v1.w; \
    h += f[p][8]*v2.x + f[p][9]*v2.y + f[p][10]*v2.z + f[p][11]*v2.w; \
    h += f[p][12]*v3.x + f[p][13]*v3.y + f[p][14]*v3.z + f[p][15]*v3.w; \
    h += cx[p]*v4.x + cy[p]*v4.y + cz[p]*v4.z; \
    ACC += fmaxf(h, 0.f) * w2j; }

// grid (ceil(N/1024), 16): 8 instances per block -> 1568 blocks (occupancy fix)
__global__ __launch_bounds__(256)
void k_mask(const float* __restrict__ maskf, const float* __restrict__ coords,
            const float* __restrict__ Vt, float* __restrict__ out,
            int N, int ostride) {
    __shared__ float Vs[352];
    int tid = threadIdx.x;
    int nb0 = blockIdx.x * 1024;
    float f[4][16], cx[4], cy[4], cz[4];
    bool val[4];
#pragma unroll
    for (int p = 0; p < 4; p++) {
        int n = nb0 + p * 256 + tid;
        val[p] = (n < N);
        if (val[p]) {
            const float4* fr = (const float4*)(maskf + (size_t)n * 16);
            float4 a = fr[0], b = fr[1], c = fr[2], d = fr[3];
            f[p][0]=a.x; f[p][1]=a.y; f[p][2]=a.z; f[p][3]=a.w;
            f[p][4]=b.x; f[p][5]=b.y; f[p][6]=b.z; f[p][7]=b.w;
            f[p][8]=c.x; f[p][9]=c.y; f[p][10]=c.z; f[p][11]=c.w;
            f[p][12]=d.x; f[p][13]=d.y; f[p][14]=d.z; f[p][15]=d.w;
            cx[p]=coords[(size_t)n*3]; cy[p]=coords[(size_t)n*3+1]; cz[p]=coords[(size_t)n*3+2];
        } else {
#pragma unroll
            for (int k = 0; k < 16; k++) f[p][k] = 0.f;
            cx[p] = cy[p] = cz[p] = 0.f;
        }
    }
    int ibase = blockIdx.y * 8;
    for (int ii = 0; ii < 8; ii++) {
        int i = ibase + ii;
        __syncthreads();
        for (int t = tid; t < 352; t += 256) Vs[t] = Vt[(size_t)i * 352 + t];
        __syncthreads();
        float acc0 = 0.f, acc1 = 0.f, acc2 = 0.f, acc3 = 0.f;
#pragma unroll 4
        for (int j = 0; j < 16; j++) {
            const float* vj = &Vs[j * 20];
            float4 v0 = *(const float4*)(vj);
            float4 v1 = *(const float4*)(vj + 4);
            float4 v2 = *(const float4*)(vj + 8);
            float4 v3 = *(const float4*)(vj + 12);
            float4 v4 = *(const float4*)(vj + 16);
            float w2j = Vs[320 + j];
            MASK_H(0, acc0) MASK_H(1, acc1) MASK_H(2, acc2) MASK_H(3, acc3)
        }
        float b2 = Vs[336];
        size_t rb = (size_t)i * ostride + nb0 + tid;
        if (val[0]) out[rb]         = 1.f / (1.f + __expf(-(acc0 + b2)));
        if (val[1]) out[rb + 256]   = 1.f / (1.f + __expf(-(acc1 + b2)));
        if (val[2]) out[rb + 512]   = 1.f / (1.f + __expf(-(acc2 + b2)));
        if (val[3]) out[rb + 768]   = 1.f / (1.f + __expf(-(acc3 + b2)));
    }
}

// ============================== merge tower ===============================
__global__ __launch_bounds__(128)
void k_merge1(const float* __restrict__ featw, const float* __restrict__ Wg,
              float* __restrict__ Z, float* __restrict__ stats_out) {
    __shared__ float F[128 * 36];
    int tid = threadIdx.x;
    for (int t = tid; t < 128 * 36; t += 128) F[t] = featw[t];
    __syncthreads();
    int id = blockIdx.x * 128 + tid;
    int a = id >> 7, b = id & 127;
    float d[35];
#pragma unroll
    for (int k = 0; k < 35; k++) d[k] = fmaxf(fabsf(F[a * 36 + k] - F[b * 36 + k]), 1e-6f);
    float z[35];
#pragma unroll
    for (int j = 0; j < 35; j++) z[j] = 0.f;
    for (int k = 0; k < 35; k++) {
        float dk = d[k];
        const float* wr = Wg + k * 35;
#pragma unroll
        for (int j = 0; j < 35; j++) z[j] += dk * wr[j];
    }
#pragma unroll
    for (int j = 0; j < 35; j++) {
        float s = z[j], q = z[j] * z[j];
#pragma unroll
        for (int off = 32; off > 0; off >>= 1) { s += __shfl_down(s, off); q += __shfl_down(q, off); }
        if ((tid & 63) == 0) { atomicAdd(&stats_out[j], s); atomicAdd(&stats_out[35 + j], q); }
    }
    float* zr = Z + (size_t)id * 36;
#pragma unroll
    for (int j = 0; j < 35; j++) zr[j] = z[j];
}

__global__ __launch_bounds__(128)
void k_merge_mid(const float* __restrict__ Zin, const float* __restrict__ Wg,
                 float* __restrict__ Zout, const float* __restrict__ stats_in,
                 float* __restrict__ stats_out) {
    __shared__ float nrm[70];
    int tid = threadIdx.x;
    if (tid < 35) {
        float s = stats_in[tid], q = stats_in[35 + tid];
        float m = s * (1.f / 16384.f);
        float v = q * (1.f / 16384.f) - m * m;
        nrm[tid] = m; nrm[35 + tid] = rsqrtf(v + EPSB);
    }
    __syncthreads();
    int id = blockIdx.x * 128 + tid;
    const float* zi = Zin + (size_t)id * 36;
    float x[35];
#pragma unroll
    for (int k = 0; k < 35; k++) x[k] = fmaxf((zi[k] - nrm[k]) * nrm[35 + k], 0.f);
    float z[35];
#pragma unroll
    for (int j = 0; j < 35; j++) z[j] = 0.f;
    for (int k = 0; k < 35; k++) {
        float dk = x[k];
        const float* wr = Wg + k * 35;
#pragma unroll
        for (int j = 0; j < 35; j++) z[j] += dk * wr[j];
    }
#pragma unroll
    for (int j = 0; j < 35; j++) {
        float s = z[j], q = z[j] * z[j];
#pragma unroll
        for (int off = 32; off > 0; off >>= 1) { s += __shfl_down(s, off); q += __shfl_down(q, off); }
        if ((tid & 63) == 0) { atomicAdd(&stats_out[j], s); atomicAdd(&stats_out[35 + j], q); }
    }
    float* zr = Zout + (size_t)id * 36;
#pragma unroll
    for (int j = 0; j < 35; j++) zr[j] = z[j];
}

__global__ __launch_bounds__(128)
void k_merge_out(const float* __restrict__ Zin, const float* __restrict__ Wout,
                 const float* __restrict__ bout, const float* __restrict__ stats_in,
                 const int* __restrict__ cand_batch, float* __restrict__ out,
                 int N, int ostride) {
    __shared__ float nrm[70];
    __shared__ int cb[128];
    int tid = threadIdx.x;
    if (tid < 35) {
        float s = stats_in[tid], q = stats_in[35 + tid];
        float m = s * (1.f / 16384.f);
        float v = q * (1.f / 16384.f) - m * m;
        nrm[tid] = m; nrm[35 + tid] = rsqrtf(v + EPSB);
    }
    cb[tid] = cand_batch[tid];
    __syncthreads();
    int id = blockIdx.x * 128 + tid;
    int a = id >> 7, b = id & 127;
    const float* zi = Zin + (size_t)id * 36;
    float s = bout[0];
    for (int k = 0; k < 35; k++)
        s += fmaxf((zi[k] - nrm[k]) * nrm[35 + k], 0.f) * Wout[k];
    float v = 1.f / (1.f + __expf(-s));
    if (cb[a] != cb[b]) v = 0.f;
    out[(size_t)a * ostride + N + b] = v;
}

// =============================== launcher =================================
extern "C" void kernel_launch(void* const* d_in, const int* in_sizes, int n_in,
                              void* d_out, int out_size, void* d_ws, size_t ws_size,
                              hipStream_t stream) {
    const float* of     = (const float*)d_in[0];
    const float* coords = (const float*)d_in[1];
    const float* heat   = (const float*)d_in[2];
    const int*   bidx   = (const int*)d_in[3];
    const float* Wm     = (const float*)d_in[4];
    const float* Wm_out = (const float*)d_in[5];
    const float* bm_out = (const float*)d_in[6];
    const float* Wk     = (const float*)d_in[7];
    const float* Wk_out = (const float*)d_in[8];
    const float* bk_out = (const float*)d_in[9];
    const float* Wg     = (const float*)d_in[10];
    const float* Wg_out = (const float*)d_in[11];
    const float* bg_out = (const float*)d_in[12];
    const float* Wwg    = (const float*)d_in[13];
    const float* bwg    = (const float*)d_in[14];
    float* out = (float*)d_out;
    float* ws  = (float*)d_ws;

    int N = in_sizes[0] / 32;          // 100000
    int ostride = N + 128;             // 100128

    float* maskf = ws + OFF_MASKF;
    float* kernf = ws + OFF_KERNF;
    float* stats = ws + OFF_STATS;
    float* Vt    = ws + OFF_VT;
    float* featw = ws + OFF_FEATW;
    float* mz1   = ws + OFF_MZ1;
    float* mz2   = ws + OFF_MZ2;
    int*   topk  = (int*)(ws + OFF_INT);
    int*   cand_batch = topk + 128;

    // tower ping-pong buffers live inside d_out (overwritten before epilogue writes)
    float* bufA = out;
    float* bufB = out + (size_t)N * 32;

    dim3 tg((N + 255) / 256);

    k_zero<<<1, 1024, 0, stream>>>(stats);
    k_nms<<<4, 1024, 0, stream>>>(heat, coords, bidx, N, topk);
    // mask tower
    k_tower<32><<<tg, 256, 0, stream>>>(of,   Wm,        nullptr, bufA,  nullptr,     stats + 0,   N);
    k_tower<32><<<tg, 256, 0, stream>>>(bufA, Wm + 1024, nullptr, bufB,  stats + 0,   stats + 64,  N);
    k_tower<32><<<tg, 256, 0, stream>>>(bufB, Wm + 2048, nullptr, bufA,  stats + 64,  stats + 128, N);
    k_tower<16><<<tg, 256, 0, stream>>>(bufA, Wm_out,    bm_out,  maskf, stats + 128, nullptr,     N);
    // kernel tower
    k_tower<32><<<tg, 256, 0, stream>>>(of,   Wk,        nullptr, bufA,  nullptr,     stats + 192, N);
    k_tower<32><<<tg, 256, 0, stream>>>(bufA, Wk + 1024, nullptr, bufB,  stats + 192, stats + 256, N);
    k_tower<32><<<tg, 256, 0, stream>>>(bufB, Wk + 2048, nullptr, bufA,  stats + 256, stats + 320, N);
    k_tower<16><<<tg, 256, 0, stream>>>(bufA, Wk_out,    bk_out,  kernf, stats + 320, nullptr,     N);

    k_prep<<<128, 384, 0, stream>>>(topk, coords, bidx, maskf, kernf, Wwg, bwg,
                                    Vt, featw, cand_batch);
    k_mask<<<dim3((N + 1023) / 1024, 16), 256, 0, stream>>>(maskf, coords, Vt, out, N, ostride);

    k_merge1<<<128, 128, 0, stream>>>(featw, Wg, mz1, stats + 384);
    k_merge_mid<<<128, 128, 0, stream>>>(mz1, Wg + 1225, mz2, stats + 384, stats + 454);
    k_merge_mid<<<128, 128, 0, stream>>>(mz2, Wg + 2450, mz1, stats + 454, stats + 524);
    k_merge_out<<<128, 128, 0, stream>>>(mz1, Wg_out, bg_out, stats + 524, cand_batch,
                                         out, N, ostride);
}

// Round 3
// 784.162 us; speedup vs baseline: 2.3105x; 1.1930x over previous
//
#include <hip/hip_runtime.h>
#include <math.h>
#include <limits.h>

#define EPSB 1e-5f
#define R2C  0.09f

// ---- workspace offsets (floats). Total ~4.44M floats = ~17.8 MB ----
#define OFF_MASKF 0          // N*16
#define OFF_KERNF 1600000    // N*16
#define OFF_STATS 3200000    // 1024 doubles (2048 float slots)
#define OFF_VT    3202048    // 128*352
#define OFF_FEATW 3247104    // 128*36
#define OFF_MZ1   3251712    // 16384*36
#define OFF_MZ2   3841536    // 16384*36
#define OFF_INT   4431360    // 256 ints (topk 128 | cand_batch 128)

// =============================== zero stats ===============================
__global__ void k_zero(double* stats) {
    int t = threadIdx.x;
    for (int i = t; i < 1024; i += 256) stats[i] = 0.0;
}

// ============================ fused tower layer ===========================
// blockIdx.y = tower (0: mask, 1: kernel). Stats are doubles, offset t*192.
template <int COLS>
__global__ __launch_bounds__(256)
void k_tower2(const float* __restrict__ X0, const float* __restrict__ X1,
              const float* __restrict__ W0, const float* __restrict__ W1,
              const float* __restrict__ b0, const float* __restrict__ b1,
              float* __restrict__ Y0, float* __restrict__ Y1,
              const double* __restrict__ stats_in, double* __restrict__ stats_out,
              int N) {
    __shared__ float As[256 * 33];
    __shared__ float mrs[64];
    __shared__ float red[256];
    int tid = threadIdx.x;
    int tw = blockIdx.y;
    const float* X = tw ? X1 : X0;
    const float* W = tw ? W1 : W0;
    const float* bias = tw ? b1 : b0;
    float* Y = tw ? Y1 : Y0;
    const double* sin_ = stats_in ? stats_in + tw * 192 : nullptr;
    double* sout = stats_out ? stats_out + tw * 192 : nullptr;

    if (sin_ && tid < 32) {
        double s = sin_[tid], q = sin_[32 + tid];
        double m = s / (double)N;
        double v = q / (double)N - m * m;
        mrs[tid] = (float)m; mrs[32 + tid] = (float)rsqrt(v + (double)EPSB);
    }
    __syncthreads();
    int rbase = blockIdx.x * 256;
    int rmax = N - rbase; if (rmax > 256) rmax = 256;
    bool nrm = (sin_ != nullptr);
    // ---- coalesced stage-in (+BN/ReLU) ----
    const float4* Xv = (const float4*)(X + (size_t)rbase * 32);
    for (int f = tid; f < 2048; f += 256) {
        int r = f >> 3, c0 = (f & 7) * 4;
        float4 v = make_float4(0.f, 0.f, 0.f, 0.f);
        if (r < rmax) v = Xv[f];
        float e[4] = {v.x, v.y, v.z, v.w};
        float* dst = &As[r * 33 + c0];
#pragma unroll
        for (int u = 0; u < 4; u++) {
            float t = e[u];
            if (nrm) t = fmaxf((t - mrs[c0 + u]) * mrs[32 + c0 + u], 0.f);
            dst[u] = t;
        }
    }
    __syncthreads();
    // ---- compute: one row per thread ----
    float acc[COLS];
#pragma unroll
    for (int j = 0; j < COLS; j++) acc[j] = 0.f;
    if (bias) {
#pragma unroll
        for (int j = 0; j < COLS; j++) acc[j] = bias[j];
    }
#pragma unroll 4
    for (int k = 0; k < 32; k++) {
        float a = As[tid * 33 + k];
        const float* wr = W + k * COLS;   // wave-uniform -> scalar loads
#pragma unroll
        for (int j = 0; j < COLS; j++) acc[j] = fmaf(a, wr[j], acc[j]);
    }
    // ---- BN stats (sum, sumsq per column), double accumulation ----
    if (sout) {
        int wv = tid >> 6;
#pragma unroll
        for (int j = 0; j < 32; j++) {
            float s = acc[j], q = acc[j] * acc[j];
#pragma unroll
            for (int off = 32; off > 0; off >>= 1) {
                s += __shfl_down(s, off);
                q += __shfl_down(q, off);
            }
            if ((tid & 63) == 0) { red[wv * 64 + j] = s; red[wv * 64 + 32 + j] = q; }
        }
        __syncthreads();
        if (tid < 64) {
            double s = (double)red[tid] + (double)red[64 + tid] +
                       (double)red[128 + tid] + (double)red[192 + tid];
            atomicAdd(&sout[tid], s);
        }
    }
    // ---- stage-out through LDS, coalesced global write ----
    __syncthreads();
#pragma unroll
    for (int j = 0; j < COLS; j++) As[tid * 33 + j] = acc[j];
    __syncthreads();
    constexpr int C4 = COLS / 4;
    for (int f = tid; f < 256 * C4; f += 256) {
        int r = f / C4, c0 = (f % C4) * 4;
        if (r < rmax) {
            const float* sp = &As[r * 33 + c0];
            float4 o = {sp[0], sp[1], sp[2], sp[3]};
            *(float4*)(Y + (size_t)(rbase + r) * COLS + c0) = o;
        }
    }
}

// ================================= NMS ====================================
// One block / batch: histogram-threshold to <=1088 candidates, then greedy
// selection by ONE WAVE holding all candidates in registers (no barriers).
#define NBINS 2048
#define NMC   1024
#define NCAP  1088
#define SLOTS 17
__global__ __launch_bounds__(256)
void k_nms(const float* __restrict__ heat, const float* __restrict__ coords,
           const int* __restrict__ bidx, int N, int* __restrict__ topk) {
    __shared__ int   hist[NBINS];
    __shared__ float ch[NCAP], cxs[NCAP], cys[NCAP], czs[NCAP];
    __shared__ int   cid[NCAP];
    __shared__ int   sh_s, sh_e, sh_T, sh_cnt;
    __shared__ float sh_val;
    __shared__ float rv[4]; __shared__ int ri[4];
    __shared__ float fbx[32], fby[32], fbz[32];
    int b = blockIdx.x, tid = threadIdx.x;
    if (tid == 0) {
        int lo = 0, hi = N;
        while (lo < hi) { int m = (lo + hi) >> 1; if (bidx[m] < b) lo = m + 1; else hi = m; }
        sh_s = lo;
        lo = 0; hi = N;
        while (lo < hi) { int m = (lo + hi) >> 1; if (bidx[m] < b + 1) lo = m + 1; else hi = m; }
        sh_e = lo;
    }
    __syncthreads();
    int s = sh_s, e = sh_e, nb = e - s;
    if (nb <= 0) {
        if (tid < 32) topk[b * 32 + tid] = 0;
        return;
    }
    for (int i = tid; i < NBINS; i += 256) hist[i] = 0;
    __syncthreads();
    for (int n = s + tid; n < e; n += 256) {
        float h = heat[n];
        int bin = (int)(h * (float)NBINS);
        bin = min(max(bin, 0), NBINS - 1);
        atomicAdd(&hist[bin], 1);
    }
    __syncthreads();
    // suffix-sum (Hillis-Steele), 8 bins/thread
    for (int off = 1; off < NBINS; off <<= 1) {
        int v[8];
#pragma unroll
        for (int u = 0; u < 8; u++) {
            int i = tid + u * 256;
            v[u] = hist[i] + ((i + off < NBINS) ? hist[i + off] : 0);
        }
        __syncthreads();
#pragma unroll
        for (int u = 0; u < 8; u++) hist[tid + u * 256] = v[u];
        __syncthreads();
    }
    int Meff = min(NMC, nb);
#pragma unroll
    for (int u = 0; u < 8; u++) {
        int i = tid + u * 256;
        if (hist[i] >= Meff && (i == NBINS - 1 || hist[i + 1] < Meff)) sh_T = i;
    }
    if (tid == 0) sh_cnt = 0;
    __syncthreads();
    int T = sh_T;
    float thr = (float)T * (1.0f / (float)NBINS);
    for (int n = s + tid; n < e; n += 256) {
        float h = heat[n];
        int bin = (int)(h * (float)NBINS);
        bin = min(max(bin, 0), NBINS - 1);
        if (bin >= T) {
            int p = atomicAdd(&sh_cnt, 1);
            if (p < NCAP) {
                ch[p] = h; cid[p] = n;
                cxs[p] = coords[(size_t)n * 3 + 0];
                cys[p] = coords[(size_t)n * 3 + 1];
                czs[p] = coords[(size_t)n * 3 + 2];
            }
        }
    }
    __syncthreads();
    int C = min(sh_cnt, NCAP);
    bool overflow = (sh_cnt > NCAP);
    // ---- selection: wave 0 only, all candidates in registers ----
    if (tid < 64) {
        float hh[SLOTS], xx[SLOTS], yy[SLOTS], zz[SLOTS];
        int ii[SLOTS];
#pragma unroll
        for (int m = 0; m < SLOTS; m++) {
            int i = m * 64 + tid;
            if (i < C) { hh[m] = ch[i]; xx[m] = cxs[i]; yy[m] = cys[i]; zz[m] = czs[i]; ii[m] = cid[i]; }
            else { hh[m] = -INFINITY; xx[m] = 1e30f; yy[m] = 1e30f; zz[m] = 1e30f; ii[m] = INT_MAX; }
        }
        float last = -INFINITY;
        for (int t = 0; t < 32; t++) {
            float bv = -INFINITY, bx = 0.f, by = 0.f, bz = 0.f;
            int bo = INT_MAX;
#pragma unroll
            for (int m = 0; m < SLOTS; m++) {
                bool c = (hh[m] > bv) || (hh[m] == bv && ii[m] < bo);
                if (c) { bv = hh[m]; bo = ii[m]; bx = xx[m]; by = yy[m]; bz = zz[m]; }
            }
#pragma unroll
            for (int off = 32; off > 0; off >>= 1) {
                float ov = __shfl_down(bv, off);
                int   oo = __shfl_down(bo, off);
                float ox = __shfl_down(bx, off);
                float oy = __shfl_down(by, off);
                float oz = __shfl_down(bz, off);
                bool c = (ov > bv) || (ov == bv && oo < bo);
                if (c) { bv = ov; bo = oo; bx = ox; by = oy; bz = oz; }
            }
            bv = __shfl(bv, 0); bo = __shfl(bo, 0);
            bx = __shfl(bx, 0); by = __shfl(by, 0); bz = __shfl(bz, 0);
            if (tid == 0) topk[b * 32 + t] = bo;
            last = bv;
#pragma unroll
            for (int m = 0; m < SLOTS; m++) {
                float dx = xx[m] - bx, dy = yy[m] - by, dz = zz[m] - bz;
                if (dx * dx + dy * dy + dz * dz < R2C) hh[m] = -INFINITY;
            }
        }
        if (tid == 0) sh_val = last;
    }
    __syncthreads();
    bool sound = (!overflow) && (C > 0) && (sh_val >= thr);
    if (!sound) {
        // brute-force exact fallback (essentially never taken)
        for (int t = 0; t < 32; t++) {
            float bv = -INFINITY; int bo = INT_MAX;
            for (int n = s + tid; n < e; n += 256) {
                float x = coords[(size_t)n * 3], y = coords[(size_t)n * 3 + 1], z = coords[(size_t)n * 3 + 2];
                bool sup = false;
                for (int u = 0; u < t; u++) {
                    float dx = x - fbx[u], dy = y - fby[u], dz = z - fbz[u];
                    if (dx * dx + dy * dy + dz * dz < R2C) { sup = true; break; }
                }
                if (!sup) {
                    float h = heat[n];
                    if (h > bv || (h == bv && n < bo)) { bv = h; bo = n; }
                }
            }
#pragma unroll
            for (int off = 32; off > 0; off >>= 1) {
                float ov = __shfl_down(bv, off); int oo = __shfl_down(bo, off);
                if (ov > bv || (ov == bv && oo < bo)) { bv = ov; bo = oo; }
            }
            if ((tid & 63) == 0) { int w = tid >> 6; rv[w] = bv; ri[w] = bo; }
            __syncthreads();
            if (tid == 0) {
                bv = rv[0]; bo = ri[0];
                for (int w = 1; w < 4; w++)
                    if (rv[w] > bv || (rv[w] == bv && ri[w] < bo)) { bv = rv[w]; bo = ri[w]; }
                if (bo == INT_MAX) bo = 0;
                topk[b * 32 + t] = bo;
                fbx[t] = coords[(size_t)bo * 3];
                fby[t] = coords[(size_t)bo * 3 + 1];
                fbz[t] = coords[(size_t)bo * 3 + 2];
            }
            __syncthreads();
        }
    }
}

// ============================ instance prep ===============================
__global__ __launch_bounds__(384)
void k_prep(const int* __restrict__ topk, const float* __restrict__ coords,
            const int* __restrict__ bidx, const float* __restrict__ maskf,
            const float* __restrict__ kernf, const float* __restrict__ Wwg,
            const float* __restrict__ bwg, float* __restrict__ Vt,
            float* __restrict__ featw, int* __restrict__ cand_batch) {
    __shared__ float ck[16], cm[16], ctr[3], wrow[337];
    int i = blockIdx.x, tid = threadIdx.x;
    int idx = topk[i];
    if (tid < 16) { ck[tid] = kernf[(size_t)idx * 16 + tid]; cm[tid] = maskf[(size_t)idx * 16 + tid]; }
    else if (tid < 19) ctr[tid - 16] = coords[(size_t)idx * 3 + (tid - 16)];
    else if (tid == 19) cand_batch[i] = bidx[idx];
    __syncthreads();
    for (int c = tid; c < 337; c += 384) {
        float acc = bwg[c];
#pragma unroll
        for (int m = 0; m < 16; m++) acc += ck[m] * Wwg[m * 337 + c];
        wrow[c] = acc;
    }
    __syncthreads();
    for (int t = tid; t < 352; t += 384) {
        float v;
        if (t < 320) {
            int j = t / 20, k = t - j * 20;
            if (k < 19) v = wrow[k * 16 + j];
            else {
                v = wrow[304 + j];
#pragma unroll
                for (int p = 0; p < 3; p++) v -= ctr[p] * wrow[(16 + p) * 16 + j];
            }
        } else if (t < 336) v = wrow[320 + (t - 320)];
        else if (t == 336) v = wrow[336];
        else v = 0.f;
        Vt[(size_t)i * 352 + t] = v;
    }
    for (int t = tid; t < 36; t += 384)
        featw[i * 36 + t] = (t < 16) ? ck[t] : (t < 32) ? cm[t - 16] : (t < 35) ? ctr[t - 32] : 0.f;
}

// ============================== mask heads ================================
#define MASK_H(p, ACC) { \
    float h = v4.w; \
    h += f[p][0]*v0.x + f[p][1]*v0.y + f[p][2]*v0.z + f[p][3]*v0.w; \
    h += f[p][4]*v1.x + f[p][5]*v1.y + f[p][6]*v1.z + f[p][7]*v1.w; \
    h += f[p][8]*v2.x + f[p][9]*v2.y + f[p][10]*v2.z + f[p][11]*v2.w; \
    h += f[p][12]*v3.x + f[p][13]*v3.y + f[p][14]*v3.z + f[p][15]*v3.w; \
    h += cx[p]*v4.x + cy[p]*v4.y + cz[p]*v4.z; \
    ACC += fmaxf(h, 0.f) * w2j; }

// launch_bounds(256,2): VGPR cap 256 so f[4][16] stays resident (68-VGPR
// allocation at (256,default) forced reloads inside the j-loop -> 41 TF).
__global__ __launch_bounds__(256, 2)
void k_mask(const float* __restrict__ maskf, const float* __restrict__ coords,
            const float* __restrict__ Vt, float* __restrict__ out,
            int N, int ostride) {
    __shared__ float Vs[352];
    int tid = threadIdx.x;
    int nb0 = blockIdx.x * 1024;
    float f[4][16], cx[4], cy[4], cz[4];
    bool val[4];
#pragma unroll
    for (int p = 0; p < 4; p++) {
        int n = nb0 + p * 256 + tid;
        val[p] = (n < N);
        if (val[p]) {
            const float4* fr = (const float4*)(maskf + (size_t)n * 16);
            float4 a = fr[0], b = fr[1], c = fr[2], d = fr[3];
            f[p][0]=a.x; f[p][1]=a.y; f[p][2]=a.z; f[p][3]=a.w;
            f[p][4]=b.x; f[p][5]=b.y; f[p][6]=b.z; f[p][7]=b.w;
            f[p][8]=c.x; f[p][9]=c.y; f[p][10]=c.z; f[p][11]=c.w;
            f[p][12]=d.x; f[p][13]=d.y; f[p][14]=d.z; f[p][15]=d.w;
            cx[p]=coords[(size_t)n*3]; cy[p]=coords[(size_t)n*3+1]; cz[p]=coords[(size_t)n*3+2];
        } else {
#pragma unroll
            for (int k = 0; k < 16; k++) f[p][k] = 0.f;
            cx[p] = cy[p] = cz[p] = 0.f;
        }
    }
    int ibase = blockIdx.y * 8;
    for (int ii = 0; ii < 8; ii++) {
        int i = ibase + ii;
        __syncthreads();
        for (int t = tid; t < 352; t += 256) Vs[t] = Vt[(size_t)i * 352 + t];
        __syncthreads();
        float acc0 = 0.f, acc1 = 0.f, acc2 = 0.f, acc3 = 0.f;
#pragma unroll 4
        for (int j = 0; j < 16; j++) {
            const float* vj = &Vs[j * 20];
            float4 v0 = *(const float4*)(vj);
            float4 v1 = *(const float4*)(vj + 4);
            float4 v2 = *(const float4*)(vj + 8);
            float4 v3 = *(const float4*)(vj + 12);
            float4 v4 = *(const float4*)(vj + 16);
            float w2j = Vs[320 + j];
            MASK_H(0, acc0) MASK_H(1, acc1) MASK_H(2, acc2) MASK_H(3, acc3)
        }
        float b2 = Vs[336];
        size_t rb = (size_t)i * ostride + nb0 + tid;
        if (val[0]) out[rb]         = 1.f / (1.f + __expf(-(acc0 + b2)));
        if (val[1]) out[rb + 256]   = 1.f / (1.f + __expf(-(acc1 + b2)));
        if (val[2]) out[rb + 512]   = 1.f / (1.f + __expf(-(acc2 + b2)));
        if (val[3]) out[rb + 768]   = 1.f / (1.f + __expf(-(acc3 + b2)));
    }
}

// ============================== merge tower ===============================
__global__ __launch_bounds__(128)
void k_merge1(const float* __restrict__ featw, const float* __restrict__ Wg,
              float* __restrict__ Z, double* __restrict__ stats_out) {
    __shared__ float F[128 * 36];
    int tid = threadIdx.x;
    for (int t = tid; t < 128 * 36; t += 128) F[t] = featw[t];
    __syncthreads();
    int id = blockIdx.x * 128 + tid;
    int a = id >> 7, b = id & 127;
    float d[35];
#pragma unroll
    for (int k = 0; k < 35; k++) d[k] = fmaxf(fabsf(F[a * 36 + k] - F[b * 36 + k]), 1e-6f);
    float z[35];
#pragma unroll
    for (int j = 0; j < 35; j++) z[j] = 0.f;
    for (int k = 0; k < 35; k++) {
        float dk = d[k];
        const float* wr = Wg + k * 35;
#pragma unroll
        for (int j = 0; j < 35; j++) z[j] += dk * wr[j];
    }
#pragma unroll
    for (int j = 0; j < 35; j++) {
        float s = z[j], q = z[j] * z[j];
#pragma unroll
        for (int off = 32; off > 0; off >>= 1) { s += __shfl_down(s, off); q += __shfl_down(q, off); }
        if ((tid & 63) == 0) { atomicAdd(&stats_out[j], (double)s); atomicAdd(&stats_out[35 + j], (double)q); }
    }
    float* zr = Z + (size_t)id * 36;
#pragma unroll
    for (int j = 0; j < 35; j++) zr[j] = z[j];
}

__global__ __launch_bounds__(128)
void k_merge_mid(const float* __restrict__ Zin, const float* __restrict__ Wg,
                 float* __restrict__ Zout, const double* __restrict__ stats_in,
                 double* __restrict__ stats_out) {
    __shared__ float nrm[70];
    int tid = threadIdx.x;
    if (tid < 35) {
        double s = stats_in[tid], q = stats_in[35 + tid];
        double m = s * (1.0 / 16384.0);
        double v = q * (1.0 / 16384.0) - m * m;
        nrm[tid] = (float)m; nrm[35 + tid] = (float)rsqrt(v + (double)EPSB);
    }
    __syncthreads();
    int id = blockIdx.x * 128 + tid;
    const float* zi = Zin + (size_t)id * 36;
    float x[35];
#pragma unroll
    for (int k = 0; k < 35; k++) x[k] = fmaxf((zi[k] - nrm[k]) * nrm[35 + k], 0.f);
    float z[35];
#pragma unroll
    for (int j = 0; j < 35; j++) z[j] = 0.f;
    for (int k = 0; k < 35; k++) {
        float dk = x[k];
        const float* wr = Wg + k * 35;
#pragma unroll
        for (int j = 0; j < 35; j++) z[j] += dk * wr[j];
    }
#pragma unroll
    for (int j = 0; j < 35; j++) {
        float s = z[j], q = z[j] * z[j];
#pragma unroll
        for (int off = 32; off > 0; off >>= 1) { s += __shfl_down(s, off); q += __shfl_down(q, off); }
        if ((tid & 63) == 0) { atomicAdd(&stats_out[j], (double)s); atomicAdd(&stats_out[35 + j], (double)q); }
    }
    float* zr = Zout + (size_t)id * 36;
#pragma unroll
    for (int j = 0; j < 35; j++) zr[j] = z[j];
}

__global__ __launch_bounds__(128)
void k_merge_out(const float* __restrict__ Zin, const float* __restrict__ Wout,
                 const float* __restrict__ bout, const double* __restrict__ stats_in,
                 const int* __restrict__ cand_batch, float* __restrict__ out,
                 int N, int ostride) {
    __shared__ float nrm[70];
    __shared__ int cb[128];
    int tid = threadIdx.x;
    if (tid < 35) {
        double s = stats_in[tid], q = stats_in[35 + tid];
        double m = s * (1.0 / 16384.0);
        double v = q * (1.0 / 16384.0) - m * m;
        nrm[tid] = (float)m; nrm[35 + tid] = (float)rsqrt(v + (double)EPSB);
    }
    cb[tid] = cand_batch[tid];
    __syncthreads();
    int id = blockIdx.x * 128 + tid;
    int a = id >> 7, b = id & 127;
    const float* zi = Zin + (size_t)id * 36;
    float s = bout[0];
    for (int k = 0; k < 35; k++)
        s += fmaxf((zi[k] - nrm[k]) * nrm[35 + k], 0.f) * Wout[k];
    float v = 1.f / (1.f + __expf(-s));
    if (cb[a] != cb[b]) v = 0.f;
    out[(size_t)a * ostride + N + b] = v;
}

// =============================== launcher =================================
extern "C" void kernel_launch(void* const* d_in, const int* in_sizes, int n_in,
                              void* d_out, int out_size, void* d_ws, size_t ws_size,
                              hipStream_t stream) {
    const float* of     = (const float*)d_in[0];
    const float* coords = (const float*)d_in[1];
    const float* heat   = (const float*)d_in[2];
    const int*   bidx   = (const int*)d_in[3];
    const float* Wm     = (const float*)d_in[4];
    const float* Wm_out = (const float*)d_in[5];
    const float* bm_out = (const float*)d_in[6];
    const float* Wk     = (const float*)d_in[7];
    const float* Wk_out = (const float*)d_in[8];
    const float* bk_out = (const float*)d_in[9];
    const float* Wg     = (const float*)d_in[10];
    const float* Wg_out = (const float*)d_in[11];
    const float* bg_out = (const float*)d_in[12];
    const float* Wwg    = (const float*)d_in[13];
    const float* bwg    = (const float*)d_in[14];
    float* out = (float*)d_out;
    float* ws  = (float*)d_ws;

    int N = in_sizes[0] / 32;          // 100000
    int ostride = N + 128;             // 100128

    float*  maskf = ws + OFF_MASKF;
    float*  kernf = ws + OFF_KERNF;
    double* stats = (double*)(ws + OFF_STATS);
    float*  Vt    = ws + OFF_VT;
    float*  featw = ws + OFF_FEATW;
    float*  mz1   = ws + OFF_MZ1;
    float*  mz2   = ws + OFF_MZ2;
    int*    topk  = (int*)(ws + OFF_INT);
    int*    cand_batch = topk + 128;

    // tower ping-pong buffers live inside d_out (overwritten before epilogue)
    // 4 x N*32 floats = 12.8M <= out_size (12,816,384)
    float* bufAm = out;
    float* bufBm = out + (size_t)N * 32;
    float* bufAk = out + (size_t)N * 64;
    float* bufBk = out + (size_t)N * 96;

    dim3 tg2((N + 255) / 256, 2);

    k_zero<<<1, 256, 0, stream>>>(stats);
    k_nms<<<4, 256, 0, stream>>>(heat, coords, bidx, N, topk);
    // both towers per launch (blockIdx.y selects); stats offsets: +t*192
    k_tower2<32><<<tg2, 256, 0, stream>>>(of,    of,    Wm,        Wk,        nullptr, nullptr, bufAm, bufAk, nullptr,     stats + 0,  N);
    k_tower2<32><<<tg2, 256, 0, stream>>>(bufAm, bufAk, Wm + 1024, Wk + 1024, nullptr, nullptr, bufBm, bufBk, stats + 0,   stats + 64, N);
    k_tower2<32><<<tg2, 256, 0, stream>>>(bufBm, bufBk, Wm + 2048, Wk + 2048, nullptr, nullptr, bufAm, bufAk, stats + 64,  stats + 128, N);
    k_tower2<16><<<tg2, 256, 0, stream>>>(bufAm, bufAk, Wm_out,    Wk_out,    bm_out,  bk_out,  maskf, kernf, stats + 128, nullptr,    N);

    k_prep<<<128, 384, 0, stream>>>(topk, coords, bidx, maskf, kernf, Wwg, bwg,
                                    Vt, featw, cand_batch);
    k_mask<<<dim3((N + 1023) / 1024, 16), 256, 0, stream>>>(maskf, coords, Vt, out, N, ostride);

    k_merge1<<<128, 128, 0, stream>>>(featw, Wg, mz1, stats + 384);
    k_merge_mid<<<128, 128, 0, stream>>>(mz1, Wg + 1225, mz2, stats + 384, stats + 454);
    k_merge_mid<<<128, 128, 0, stream>>>(mz2, Wg + 2450, mz1, stats + 454, stats + 524);
    k_merge_out<<<128, 128, 0, stream>>>(mz1, Wg_out, bg_out, stats + 524, cand_batch,
                                         out, N, ostride);
}

// Round 4
// 762.320 us; speedup vs baseline: 2.3767x; 1.0287x over previous
//
#include <hip/hip_runtime.h>
#include <math.h>
#include <limits.h>

#define EPSB 1e-5f
#define R2C  0.09f

// ---- workspace offsets (floats). Total ~4.44M floats = ~17.8 MB ----
#define OFF_MASKF 0          // N*16
#define OFF_KERNF 1600000    // N*16
#define OFF_STATS 3200000    // 1024 doubles (2048 float slots)
#define OFF_VT    3202048    // 128*352
#define OFF_FEATW 3247104    // 128*36
#define OFF_MZ1   3251712    // 16384*36
#define OFF_MZ2   3841536    // 16384*36
#define OFF_INT   4431360    // 256 ints (topk 128 | cand_batch 128)

// ============================ fused tower layer ===========================
// blockIdx.y = tower (0: mask, 1: kernel). Stats are doubles, offset t*192.
template <int COLS>
__global__ __launch_bounds__(256)
void k_tower2(const float* __restrict__ X0, const float* __restrict__ X1,
              const float* __restrict__ W0, const float* __restrict__ W1,
              const float* __restrict__ b0, const float* __restrict__ b1,
              float* __restrict__ Y0, float* __restrict__ Y1,
              const double* __restrict__ stats_in, double* __restrict__ stats_out,
              int N) {
    __shared__ float As[256 * 33];
    __shared__ float mrs[64];
    __shared__ float red[256];
    int tid = threadIdx.x;
    int tw = blockIdx.y;
    const float* X = tw ? X1 : X0;
    const float* W = tw ? W1 : W0;
    const float* bias = tw ? b1 : b0;
    float* Y = tw ? Y1 : Y0;
    const double* sin_ = stats_in ? stats_in + tw * 192 : nullptr;
    double* sout = stats_out ? stats_out + tw * 192 : nullptr;

    if (sin_ && tid < 32) {
        double s = sin_[tid], q = sin_[32 + tid];
        double m = s / (double)N;
        double v = q / (double)N - m * m;
        mrs[tid] = (float)m; mrs[32 + tid] = (float)rsqrt(v + (double)EPSB);
    }
    __syncthreads();
    int rbase = blockIdx.x * 256;
    int rmax = N - rbase; if (rmax > 256) rmax = 256;
    bool nrm = (sin_ != nullptr);
    // ---- coalesced stage-in (+BN/ReLU) ----
    const float4* Xv = (const float4*)(X + (size_t)rbase * 32);
    for (int f = tid; f < 2048; f += 256) {
        int r = f >> 3, c0 = (f & 7) * 4;
        float4 v = make_float4(0.f, 0.f, 0.f, 0.f);
        if (r < rmax) v = Xv[f];
        float e[4] = {v.x, v.y, v.z, v.w};
        float* dst = &As[r * 33 + c0];
#pragma unroll
        for (int u = 0; u < 4; u++) {
            float t = e[u];
            if (nrm) t = fmaxf((t - mrs[c0 + u]) * mrs[32 + c0 + u], 0.f);
            dst[u] = t;
        }
    }
    __syncthreads();
    // ---- compute: one row per thread ----
    float acc[COLS];
#pragma unroll
    for (int j = 0; j < COLS; j++) acc[j] = 0.f;
    if (bias) {
#pragma unroll
        for (int j = 0; j < COLS; j++) acc[j] = bias[j];
    }
#pragma unroll 4
    for (int k = 0; k < 32; k++) {
        float a = As[tid * 33 + k];
        const float* wr = W + k * COLS;   // wave-uniform -> scalar loads
#pragma unroll
        for (int j = 0; j < COLS; j++) acc[j] = fmaf(a, wr[j], acc[j]);
    }
    // ---- BN stats (sum, sumsq per column), double accumulation ----
    if (sout) {
        int wv = tid >> 6;
#pragma unroll
        for (int j = 0; j < 32; j++) {
            float s = acc[j], q = acc[j] * acc[j];
#pragma unroll
            for (int off = 32; off > 0; off >>= 1) {
                s += __shfl_down(s, off);
                q += __shfl_down(q, off);
            }
            if ((tid & 63) == 0) { red[wv * 64 + j] = s; red[wv * 64 + 32 + j] = q; }
        }
        __syncthreads();
        if (tid < 64) {
            double s = (double)red[tid] + (double)red[64 + tid] +
                       (double)red[128 + tid] + (double)red[192 + tid];
            atomicAdd(&sout[tid], s);
        }
    }
    // ---- stage-out through LDS, coalesced global write ----
    __syncthreads();
#pragma unroll
    for (int j = 0; j < COLS; j++) As[tid * 33 + j] = acc[j];
    __syncthreads();
    constexpr int C4 = COLS / 4;
    for (int f = tid; f < 256 * C4; f += 256) {
        int r = f / C4, c0 = (f % C4) * 4;
        if (r < rmax) {
            const float* sp = &As[r * 33 + c0];
            float4 o = {sp[0], sp[1], sp[2], sp[3]};
            *(float4*)(Y + (size_t)(rbase + r) * COLS + c0) = o;
        }
    }
}

// ================================= NMS ====================================
// One block / batch: histogram-threshold to <=1088 candidates, then greedy
// selection by ONE WAVE holding all candidates in registers (no barriers).
// Also zeroes the stats buffer (k_zero folded in).
#define NBINS 2048
#define NMC   1024
#define NCAP  1088
#define SLOTS 17
__global__ __launch_bounds__(256)
void k_nms(const float* __restrict__ heat, const float* __restrict__ coords,
           const int* __restrict__ bidx, int N, int* __restrict__ topk,
           double* __restrict__ stats) {
    __shared__ int   hist[NBINS];
    __shared__ float ch[NCAP], cxs[NCAP], cys[NCAP], czs[NCAP];
    __shared__ int   cid[NCAP];
    __shared__ int   sh_s, sh_e, sh_T, sh_cnt;
    __shared__ float sh_val;
    __shared__ float rv[4]; __shared__ int ri[4];
    __shared__ float fbx[32], fby[32], fbz[32];
    int b = blockIdx.x, tid = threadIdx.x;
    // zero stats: block b covers stats[b*256 .. b*256+256)
    stats[b * 256 + tid] = 0.0;
    if (tid == 0) {
        int lo = 0, hi = N;
        while (lo < hi) { int m = (lo + hi) >> 1; if (bidx[m] < b) lo = m + 1; else hi = m; }
        sh_s = lo;
        lo = 0; hi = N;
        while (lo < hi) { int m = (lo + hi) >> 1; if (bidx[m] < b + 1) lo = m + 1; else hi = m; }
        sh_e = lo;
    }
    __syncthreads();
    int s = sh_s, e = sh_e, nb = e - s;
    if (nb <= 0) {
        if (tid < 32) topk[b * 32 + tid] = 0;
        return;
    }
    for (int i = tid; i < NBINS; i += 256) hist[i] = 0;
    __syncthreads();
    for (int n = s + tid; n < e; n += 256) {
        float h = heat[n];
        int bin = (int)(h * (float)NBINS);
        bin = min(max(bin, 0), NBINS - 1);
        atomicAdd(&hist[bin], 1);
    }
    __syncthreads();
    // suffix-sum (Hillis-Steele), 8 bins/thread
    for (int off = 1; off < NBINS; off <<= 1) {
        int v[8];
#pragma unroll
        for (int u = 0; u < 8; u++) {
            int i = tid + u * 256;
            v[u] = hist[i] + ((i + off < NBINS) ? hist[i + off] : 0);
        }
        __syncthreads();
#pragma unroll
        for (int u = 0; u < 8; u++) hist[tid + u * 256] = v[u];
        __syncthreads();
    }
    int Meff = min(NMC, nb);
#pragma unroll
    for (int u = 0; u < 8; u++) {
        int i = tid + u * 256;
        if (hist[i] >= Meff && (i == NBINS - 1 || hist[i + 1] < Meff)) sh_T = i;
    }
    if (tid == 0) sh_cnt = 0;
    __syncthreads();
    int T = sh_T;
    float thr = (float)T * (1.0f / (float)NBINS);
    for (int n = s + tid; n < e; n += 256) {
        float h = heat[n];
        int bin = (int)(h * (float)NBINS);
        bin = min(max(bin, 0), NBINS - 1);
        if (bin >= T) {
            int p = atomicAdd(&sh_cnt, 1);
            if (p < NCAP) {
                ch[p] = h; cid[p] = n;
                cxs[p] = coords[(size_t)n * 3 + 0];
                cys[p] = coords[(size_t)n * 3 + 1];
                czs[p] = coords[(size_t)n * 3 + 2];
            }
        }
    }
    __syncthreads();
    int C = min(sh_cnt, NCAP);
    bool overflow = (sh_cnt > NCAP);
    // ---- selection: wave 0 only, all candidates in registers ----
    if (tid < 64) {
        float hh[SLOTS], xx[SLOTS], yy[SLOTS], zz[SLOTS];
        int ii[SLOTS];
#pragma unroll
        for (int m = 0; m < SLOTS; m++) {
            int i = m * 64 + tid;
            if (i < C) { hh[m] = ch[i]; xx[m] = cxs[i]; yy[m] = cys[i]; zz[m] = czs[i]; ii[m] = cid[i]; }
            else { hh[m] = -INFINITY; xx[m] = 1e30f; yy[m] = 1e30f; zz[m] = 1e30f; ii[m] = INT_MAX; }
        }
        float last = -INFINITY;
        for (int t = 0; t < 32; t++) {
            float bv = -INFINITY, bx = 0.f, by = 0.f, bz = 0.f;
            int bo = INT_MAX;
#pragma unroll
            for (int m = 0; m < SLOTS; m++) {
                bool c = (hh[m] > bv) || (hh[m] == bv && ii[m] < bo);
                if (c) { bv = hh[m]; bo = ii[m]; bx = xx[m]; by = yy[m]; bz = zz[m]; }
            }
#pragma unroll
            for (int off = 32; off > 0; off >>= 1) {
                float ov = __shfl_down(bv, off);
                int   oo = __shfl_down(bo, off);
                float ox = __shfl_down(bx, off);
                float oy = __shfl_down(by, off);
                float oz = __shfl_down(bz, off);
                bool c = (ov > bv) || (ov == bv && oo < bo);
                if (c) { bv = ov; bo = oo; bx = ox; by = oy; bz = oz; }
            }
            bv = __shfl(bv, 0); bo = __shfl(bo, 0);
            bx = __shfl(bx, 0); by = __shfl(by, 0); bz = __shfl(bz, 0);
            if (tid == 0) topk[b * 32 + t] = bo;
            last = bv;
#pragma unroll
            for (int m = 0; m < SLOTS; m++) {
                float dx = xx[m] - bx, dy = yy[m] - by, dz = zz[m] - bz;
                if (dx * dx + dy * dy + dz * dz < R2C) hh[m] = -INFINITY;
            }
        }
        if (tid == 0) sh_val = last;
    }
    __syncthreads();
    bool sound = (!overflow) && (C > 0) && (sh_val >= thr);
    if (!sound) {
        // brute-force exact fallback (essentially never taken)
        for (int t = 0; t < 32; t++) {
            float bv = -INFINITY; int bo = INT_MAX;
            for (int n = s + tid; n < e; n += 256) {
                float x = coords[(size_t)n * 3], y = coords[(size_t)n * 3 + 1], z = coords[(size_t)n * 3 + 2];
                bool sup = false;
                for (int u = 0; u < t; u++) {
                    float dx = x - fbx[u], dy = y - fby[u], dz = z - fbz[u];
                    if (dx * dx + dy * dy + dz * dz < R2C) { sup = true; break; }
                }
                if (!sup) {
                    float h = heat[n];
                    if (h > bv || (h == bv && n < bo)) { bv = h; bo = n; }
                }
            }
#pragma unroll
            for (int off = 32; off > 0; off >>= 1) {
                float ov = __shfl_down(bv, off); int oo = __shfl_down(bo, off);
                if (ov > bv || (ov == bv && oo < bo)) { bv = ov; bo = oo; }
            }
            if ((tid & 63) == 0) { int w = tid >> 6; rv[w] = bv; ri[w] = bo; }
            __syncthreads();
            if (tid == 0) {
                bv = rv[0]; bo = ri[0];
                for (int w = 1; w < 4; w++)
                    if (rv[w] > bv || (rv[w] == bv && ri[w] < bo)) { bv = rv[w]; bo = ri[w]; }
                if (bo == INT_MAX) bo = 0;
                topk[b * 32 + t] = bo;
                fbx[t] = coords[(size_t)bo * 3];
                fby[t] = coords[(size_t)bo * 3 + 1];
                fbz[t] = coords[(size_t)bo * 3 + 2];
            }
            __syncthreads();
        }
    }
}

// ============================ instance prep ===============================
// Vt layout (k-major): Vt[i*352 + k*16 + j], k=0..19 (k==19 = folded bias
// row b1 - ctr.W1pos, paired with a[19]=1); [320..336) = w2; [336] = b2.
__global__ __launch_bounds__(384)
void k_prep(const int* __restrict__ topk, const float* __restrict__ coords,
            const int* __restrict__ bidx, const float* __restrict__ maskf,
            const float* __restrict__ kernf, const float* __restrict__ Wwg,
            const float* __restrict__ bwg, float* __restrict__ Vt,
            float* __restrict__ featw, int* __restrict__ cand_batch) {
    __shared__ float ck[16], cm[16], ctr[3], wrow[337];
    int i = blockIdx.x, tid = threadIdx.x;
    int idx = topk[i];
    if (tid < 16) { ck[tid] = kernf[(size_t)idx * 16 + tid]; cm[tid] = maskf[(size_t)idx * 16 + tid]; }
    else if (tid < 19) ctr[tid - 16] = coords[(size_t)idx * 3 + (tid - 16)];
    else if (tid == 19) cand_batch[i] = bidx[idx];
    __syncthreads();
    for (int c = tid; c < 337; c += 384) {
        float acc = bwg[c];
#pragma unroll
        for (int m = 0; m < 16; m++) acc += ck[m] * Wwg[m * 337 + c];
        wrow[c] = acc;
    }
    __syncthreads();
    for (int t = tid; t < 352; t += 384) {
        float v;
        if (t < 320) {
            int k = t >> 4, j = t & 15;
            if (k < 19) v = wrow[k * 16 + j];
            else {
                v = wrow[304 + j];
#pragma unroll
                for (int p = 0; p < 3; p++) v -= ctr[p] * wrow[(16 + p) * 16 + j];
            }
        } else if (t < 336) v = wrow[320 + (t - 320)];
        else if (t == 336) v = wrow[336];
        else v = 0.f;
        Vt[(size_t)i * 352 + t] = v;
    }
    for (int t = tid; t < 36; t += 384)
        featw[i * 36 + t] = (t < 16) ? ck[t] : (t < 32) ? cm[t - 16] : (t < 35) ? ctr[t - 32] : 0.f;
}

// ============================== mask heads ================================
// One point per thread: a[20] in VGPRs, h[16] accumulators, V via uniform
// pointer -> scalar (SGPR) loads. Hot loop = pure v_fmac_f32 v,s,v.
__global__ __launch_bounds__(256)
void k_mask(const float* __restrict__ maskf, const float* __restrict__ coords,
            const float* __restrict__ Vt, float* __restrict__ out,
            int N, int ostride) {
    int tid = threadIdx.x;
    int n = blockIdx.x * 256 + tid;
    bool valid = (n < N);
    float a[20];
    if (valid) {
        const float4* fr = (const float4*)(maskf + (size_t)n * 16);
        float4 A = fr[0], B = fr[1], C = fr[2], D = fr[3];
        a[0]=A.x; a[1]=A.y; a[2]=A.z; a[3]=A.w;
        a[4]=B.x; a[5]=B.y; a[6]=B.z; a[7]=B.w;
        a[8]=C.x; a[9]=C.y; a[10]=C.z; a[11]=C.w;
        a[12]=D.x; a[13]=D.y; a[14]=D.z; a[15]=D.w;
        a[16]=coords[(size_t)n*3]; a[17]=coords[(size_t)n*3+1]; a[18]=coords[(size_t)n*3+2];
    } else {
#pragma unroll
        for (int k = 0; k < 19; k++) a[k] = 0.f;
    }
    a[19] = 1.f;
    int ibase = blockIdx.y * 32;
    for (int ii = 0; ii < 32; ii++) {
        const float* __restrict__ V = Vt + (size_t)(ibase + ii) * 352;  // block-uniform -> s_load
        float h[16];
#pragma unroll
        for (int j = 0; j < 16; j++) h[j] = 0.f;
#pragma unroll
        for (int k = 0; k < 20; k++) {
            float ak = a[k];
#pragma unroll
            for (int j = 0; j < 16; j++) h[j] = fmaf(ak, V[k * 16 + j], h[j]);
        }
        float acc = V[336];
#pragma unroll
        for (int j = 0; j < 16; j++) acc = fmaf(fmaxf(h[j], 0.f), V[320 + j], acc);
        if (valid)
            out[(size_t)(ibase + ii) * ostride + n] = 1.f / (1.f + __expf(-acc));
    }
}

// ============================== merge tower ===============================
__global__ __launch_bounds__(128)
void k_merge1(const float* __restrict__ featw, const float* __restrict__ Wg,
              float* __restrict__ Z, double* __restrict__ stats_out) {
    __shared__ float F[128 * 36];
    int tid = threadIdx.x;
    for (int t = tid; t < 128 * 36; t += 128) F[t] = featw[t];
    __syncthreads();
    int id = blockIdx.x * 128 + tid;
    int a = id >> 7, b = id & 127;
    float d[35];
#pragma unroll
    for (int k = 0; k < 35; k++) d[k] = fmaxf(fabsf(F[a * 36 + k] - F[b * 36 + k]), 1e-6f);
    float z[35];
#pragma unroll
    for (int j = 0; j < 35; j++) z[j] = 0.f;
    for (int k = 0; k < 35; k++) {
        float dk = d[k];
        const float* wr = Wg + k * 35;
#pragma unroll
        for (int j = 0; j < 35; j++) z[j] += dk * wr[j];
    }
#pragma unroll
    for (int j = 0; j < 35; j++) {
        float s = z[j], q = z[j] * z[j];
#pragma unroll
        for (int off = 32; off > 0; off >>= 1) { s += __shfl_down(s, off); q += __shfl_down(q, off); }
        if ((tid & 63) == 0) { atomicAdd(&stats_out[j], (double)s); atomicAdd(&stats_out[35 + j], (double)q); }
    }
    float* zr = Z + (size_t)id * 36;
#pragma unroll
    for (int j = 0; j < 35; j++) zr[j] = z[j];
}

__global__ __launch_bounds__(128)
void k_merge_mid(const float* __restrict__ Zin, const float* __restrict__ Wg,
                 float* __restrict__ Zout, const double* __restrict__ stats_in,
                 double* __restrict__ stats_out) {
    __shared__ float nrm[70];
    int tid = threadIdx.x;
    if (tid < 35) {
        double s = stats_in[tid], q = stats_in[35 + tid];
        double m = s * (1.0 / 16384.0);
        double v = q * (1.0 / 16384.0) - m * m;
        nrm[tid] = (float)m; nrm[35 + tid] = (float)rsqrt(v + (double)EPSB);
    }
    __syncthreads();
    int id = blockIdx.x * 128 + tid;
    const float* zi = Zin + (size_t)id * 36;
    float x[35];
#pragma unroll
    for (int k = 0; k < 35; k++) x[k] = fmaxf((zi[k] - nrm[k]) * nrm[35 + k], 0.f);
    float z[35];
#pragma unroll
    for (int j = 0; j < 35; j++) z[j] = 0.f;
    for (int k = 0; k < 35; k++) {
        float dk = x[k];
        const float* wr = Wg + k * 35;
#pragma unroll
        for (int j = 0; j < 35; j++) z[j] += dk * wr[j];
    }
#pragma unroll
    for (int j = 0; j < 35; j++) {
        float s = z[j], q = z[j] * z[j];
#pragma unroll
        for (int off = 32; off > 0; off >>= 1) { s += __shfl_down(s, off); q += __shfl_down(q, off); }
        if ((tid & 63) == 0) { atomicAdd(&stats_out[j], (double)s); atomicAdd(&stats_out[35 + j], (double)q); }
    }
    float* zr = Zout + (size_t)id * 36;
#pragma unroll
    for (int j = 0; j < 35; j++) zr[j] = z[j];
}

__global__ __launch_bounds__(128)
void k_merge_out(const float* __restrict__ Zin, const float* __restrict__ Wout,
                 const float* __restrict__ bout, const double* __restrict__ stats_in,
                 const int* __restrict__ cand_batch, float* __restrict__ out,
                 int N, int ostride) {
    __shared__ float nrm[70];
    __shared__ int cb[128];
    int tid = threadIdx.x;
    if (tid < 35) {
        double s = stats_in[tid], q = stats_in[35 + tid];
        double m = s * (1.0 / 16384.0);
        double v = q * (1.0 / 16384.0) - m * m;
        nrm[tid] = (float)m; nrm[35 + tid] = (float)rsqrt(v + (double)EPSB);
    }
    cb[tid] = cand_batch[tid];
    __syncthreads();
    int id = blockIdx.x * 128 + tid;
    int a = id >> 7, b = id & 127;
    const float* zi = Zin + (size_t)id * 36;
    float s = bout[0];
    for (int k = 0; k < 35; k++)
        s += fmaxf((zi[k] - nrm[k]) * nrm[35 + k], 0.f) * Wout[k];
    float v = 1.f / (1.f + __expf(-s));
    if (cb[a] != cb[b]) v = 0.f;
    out[(size_t)a * ostride + N + b] = v;
}

// =============================== launcher =================================
extern "C" void kernel_launch(void* const* d_in, const int* in_sizes, int n_in,
                              void* d_out, int out_size, void* d_ws, size_t ws_size,
                              hipStream_t stream) {
    const float* of     = (const float*)d_in[0];
    const float* coords = (const float*)d_in[1];
    const float* heat   = (const float*)d_in[2];
    const int*   bidx   = (const int*)d_in[3];
    const float* Wm     = (const float*)d_in[4];
    const float* Wm_out = (const float*)d_in[5];
    const float* bm_out = (const float*)d_in[6];
    const float* Wk     = (const float*)d_in[7];
    const float* Wk_out = (const float*)d_in[8];
    const float* bk_out = (const float*)d_in[9];
    const float* Wg     = (const float*)d_in[10];
    const float* Wg_out = (const float*)d_in[11];
    const float* bg_out = (const float*)d_in[12];
    const float* Wwg    = (const float*)d_in[13];
    const float* bwg    = (const float*)d_in[14];
    float* out = (float*)d_out;
    float* ws  = (float*)d_ws;

    int N = in_sizes[0] / 32;          // 100000
    int ostride = N + 128;             // 100128

    float*  maskf = ws + OFF_MASKF;
    float*  kernf = ws + OFF_KERNF;
    double* stats = (double*)(ws + OFF_STATS);
    float*  Vt    = ws + OFF_VT;
    float*  featw = ws + OFF_FEATW;
    float*  mz1   = ws + OFF_MZ1;
    float*  mz2   = ws + OFF_MZ2;
    int*    topk  = (int*)(ws + OFF_INT);
    int*    cand_batch = topk + 128;

    // tower ping-pong buffers live inside d_out (overwritten before epilogue)
    float* bufAm = out;
    float* bufBm = out + (size_t)N * 32;
    float* bufAk = out + (size_t)N * 64;
    float* bufBk = out + (size_t)N * 96;

    dim3 tg2((N + 255) / 256, 2);

    k_nms<<<4, 256, 0, stream>>>(heat, coords, bidx, N, topk, stats);
    // both towers per launch (blockIdx.y selects); stats offsets: +t*192
    k_tower2<32><<<tg2, 256, 0, stream>>>(of,    of,    Wm,        Wk,        nullptr, nullptr, bufAm, bufAk, nullptr,     stats + 0,  N);
    k_tower2<32><<<tg2, 256, 0, stream>>>(bufAm, bufAk, Wm + 1024, Wk + 1024, nullptr, nullptr, bufBm, bufBk, stats + 0,   stats + 64, N);
    k_tower2<32><<<tg2, 256, 0, stream>>>(bufBm, bufBk, Wm + 2048, Wk + 2048, nullptr, nullptr, bufAm, bufAk, stats + 64,  stats + 128, N);
    k_tower2<16><<<tg2, 256, 0, stream>>>(bufAm, bufAk, Wm_out,    Wk_out,    bm_out,  bk_out,  maskf, kernf, stats + 128, nullptr,    N);

    k_prep<<<128, 384, 0, stream>>>(topk, coords, bidx, maskf, kernf, Wwg, bwg,
                                    Vt, featw, cand_batch);
    k_mask<<<dim3((N + 255) / 256, 4), 256, 0, stream>>>(maskf, coords, Vt, out, N, ostride);

    k_merge1<<<128, 128, 0, stream>>>(featw, Wg, mz1, stats + 384);
    k_merge_mid<<<128, 128, 0, stream>>>(mz1, Wg + 1225, mz2, stats + 384, stats + 454);
    k_merge_mid<<<128, 128, 0, stream>>>(mz2, Wg + 2450, mz1, stats + 454, stats + 524);
    k_merge_out<<<128, 128, 0, stream>>>(mz1, Wg_out, bg_out, stats + 524, cand_batch,
                                         out, N, ostride);
}

// Round 5
// 715.677 us; speedup vs baseline: 2.5316x; 1.0652x over previous
//
#include <hip/hip_runtime.h>
#include <math.h>
#include <limits.h>

#define EPSB 1e-5f
#define R2C  0.09f

// ---- workspace offsets (floats). Total ~4.44M floats = ~17.8 MB ----
#define OFF_MASKF 0          // N*16
#define OFF_KERNF 1600000    // N*16
#define OFF_STATS 3200000    // 1024 doubles (2048 float slots)
#define OFF_VT    3202048    // 128*352
#define OFF_FEATW 3247104    // 128*36
#define OFF_MZ1   3251712    // 16384*36
#define OFF_MZ2   3841536    // 16384*36
#define OFF_INT   4431360    // 256 ints (topk 128 | cand_batch 128)

// ============================ fused tower layer ===========================
// blockIdx.y = tower (0: mask, 1: kernel). Stats are doubles, offset t*192.
template <int COLS>
__global__ __launch_bounds__(256)
void k_tower2(const float* __restrict__ X0, const float* __restrict__ X1,
              const float* __restrict__ W0, const float* __restrict__ W1,
              const float* __restrict__ b0, const float* __restrict__ b1,
              float* __restrict__ Y0, float* __restrict__ Y1,
              const double* __restrict__ stats_in, double* __restrict__ stats_out,
              int N) {
    __shared__ float As[256 * 33];
    __shared__ float mrs[64];
    __shared__ float red[256];
    int tid = threadIdx.x;
    int tw = blockIdx.y;
    const float* X = tw ? X1 : X0;
    const float* W = tw ? W1 : W0;
    const float* bias = tw ? b1 : b0;
    float* Y = tw ? Y1 : Y0;
    const double* sin_ = stats_in ? stats_in + tw * 192 : nullptr;
    double* sout = stats_out ? stats_out + tw * 192 : nullptr;

    if (sin_ && tid < 32) {
        double s = sin_[tid], q = sin_[32 + tid];
        double m = s / (double)N;
        double v = q / (double)N - m * m;
        mrs[tid] = (float)m; mrs[32 + tid] = (float)rsqrt(v + (double)EPSB);
    }
    __syncthreads();
    int rbase = blockIdx.x * 256;
    int rmax = N - rbase; if (rmax > 256) rmax = 256;
    bool nrm = (sin_ != nullptr);
    // ---- coalesced stage-in (+BN/ReLU) ----
    const float4* Xv = (const float4*)(X + (size_t)rbase * 32);
    for (int f = tid; f < 2048; f += 256) {
        int r = f >> 3, c0 = (f & 7) * 4;
        float4 v = make_float4(0.f, 0.f, 0.f, 0.f);
        if (r < rmax) v = Xv[f];
        float e[4] = {v.x, v.y, v.z, v.w};
        float* dst = &As[r * 33 + c0];
#pragma unroll
        for (int u = 0; u < 4; u++) {
            float t = e[u];
            if (nrm) t = fmaxf((t - mrs[c0 + u]) * mrs[32 + c0 + u], 0.f);
            dst[u] = t;
        }
    }
    __syncthreads();
    // ---- compute: one row per thread ----
    float acc[COLS];
#pragma unroll
    for (int j = 0; j < COLS; j++) acc[j] = 0.f;
    if (bias) {
#pragma unroll
        for (int j = 0; j < COLS; j++) acc[j] = bias[j];
    }
#pragma unroll 4
    for (int k = 0; k < 32; k++) {
        float a = As[tid * 33 + k];
        const float* wr = W + k * COLS;   // wave-uniform -> scalar loads
#pragma unroll
        for (int j = 0; j < COLS; j++) acc[j] = fmaf(a, wr[j], acc[j]);
    }
    // ---- BN stats (sum, sumsq per column), double accumulation ----
    if (sout) {
        int wv = tid >> 6;
#pragma unroll
        for (int j = 0; j < 32; j++) {
            float s = acc[j], q = acc[j] * acc[j];
#pragma unroll
            for (int off = 32; off > 0; off >>= 1) {
                s += __shfl_down(s, off);
                q += __shfl_down(q, off);
            }
            if ((tid & 63) == 0) { red[wv * 64 + j] = s; red[wv * 64 + 32 + j] = q; }
        }
        __syncthreads();
        if (tid < 64) {
            double s = (double)red[tid] + (double)red[64 + tid] +
                       (double)red[128 + tid] + (double)red[192 + tid];
            atomicAdd(&sout[tid], s);
        }
    }
    // ---- stage-out through LDS, coalesced global write ----
    __syncthreads();
#pragma unroll
    for (int j = 0; j < COLS; j++) As[tid * 33 + j] = acc[j];
    __syncthreads();
    constexpr int C4 = COLS / 4;
    for (int f = tid; f < 256 * C4; f += 256) {
        int r = f / C4, c0 = (f % C4) * 4;
        if (r < rmax) {
            const float* sp = &As[r * 33 + c0];
            float4 o = {sp[0], sp[1], sp[2], sp[3]};
            *(float4*)(Y + (size_t)(rbase + r) * COLS + c0) = o;
        }
    }
}

// ================================= NMS ====================================
// One 1024-thread block / batch: histogram-threshold to <=1088 candidates,
// then greedy selection by ONE WAVE with all candidates in registers.
// Also zeroes the stats buffer (k_zero folded in).
#define NBINS 2048
#define NMC   1024
#define NCAP  1088
#define SLOTS 17
__global__ __launch_bounds__(1024)
void k_nms(const float* __restrict__ heat, const float* __restrict__ coords,
           const int* __restrict__ bidx, int N, int* __restrict__ topk,
           double* __restrict__ stats) {
    __shared__ int   hist[NBINS];
    __shared__ float ch[NCAP], cxs[NCAP], cys[NCAP], czs[NCAP];
    __shared__ int   cid[NCAP];
    __shared__ int   sh_s, sh_e, sh_T, sh_cnt;
    __shared__ float sh_val;
    __shared__ float rv[16]; __shared__ int ri[16];
    __shared__ float fbx[32], fby[32], fbz[32];
    int b = blockIdx.x, tid = threadIdx.x;
    // zero stats: block b covers stats[b*256 .. b*256+256)
    if (tid < 256) stats[b * 256 + tid] = 0.0;
    if (tid == 0) {
        int lo = 0, hi = N;
        while (lo < hi) { int m = (lo + hi) >> 1; if (bidx[m] < b) lo = m + 1; else hi = m; }
        sh_s = lo;
        lo = 0; hi = N;
        while (lo < hi) { int m = (lo + hi) >> 1; if (bidx[m] < b + 1) lo = m + 1; else hi = m; }
        sh_e = lo;
    }
    __syncthreads();
    int s = sh_s, e = sh_e, nb = e - s;
    if (nb <= 0) {
        if (tid < 32) topk[b * 32 + tid] = 0;
        return;
    }
    for (int i = tid; i < NBINS; i += 1024) hist[i] = 0;
    __syncthreads();
    for (int n = s + tid; n < e; n += 1024) {
        float h = heat[n];
        int bin = (int)(h * (float)NBINS);
        bin = min(max(bin, 0), NBINS - 1);
        atomicAdd(&hist[bin], 1);
    }
    __syncthreads();
    // suffix-sum (Hillis-Steele), 2 bins/thread
    for (int off = 1; off < NBINS; off <<= 1) {
        int v[2];
#pragma unroll
        for (int u = 0; u < 2; u++) {
            int i = tid + u * 1024;
            v[u] = hist[i] + ((i + off < NBINS) ? hist[i + off] : 0);
        }
        __syncthreads();
#pragma unroll
        for (int u = 0; u < 2; u++) hist[tid + u * 1024] = v[u];
        __syncthreads();
    }
    int Meff = min(NMC, nb);
#pragma unroll
    for (int u = 0; u < 2; u++) {
        int i = tid + u * 1024;
        if (hist[i] >= Meff && (i == NBINS - 1 || hist[i + 1] < Meff)) sh_T = i;
    }
    if (tid == 0) sh_cnt = 0;
    __syncthreads();
    int T = sh_T;
    float thr = (float)T * (1.0f / (float)NBINS);
    for (int n = s + tid; n < e; n += 1024) {
        float h = heat[n];
        int bin = (int)(h * (float)NBINS);
        bin = min(max(bin, 0), NBINS - 1);
        if (bin >= T) {
            int p = atomicAdd(&sh_cnt, 1);
            if (p < NCAP) {
                ch[p] = h; cid[p] = n;
                cxs[p] = coords[(size_t)n * 3 + 0];
                cys[p] = coords[(size_t)n * 3 + 1];
                czs[p] = coords[(size_t)n * 3 + 2];
            }
        }
    }
    __syncthreads();
    int C = min(sh_cnt, NCAP);
    bool overflow = (sh_cnt > NCAP);
    // ---- selection: wave 0 only, all candidates in registers ----
    if (tid < 64) {
        float hh[SLOTS], xx[SLOTS], yy[SLOTS], zz[SLOTS];
        int ii[SLOTS];
#pragma unroll
        for (int m = 0; m < SLOTS; m++) {
            int i = m * 64 + tid;
            if (i < C) { hh[m] = ch[i]; xx[m] = cxs[i]; yy[m] = cys[i]; zz[m] = czs[i]; ii[m] = cid[i]; }
            else { hh[m] = -INFINITY; xx[m] = 1e30f; yy[m] = 1e30f; zz[m] = 1e30f; ii[m] = INT_MAX; }
        }
        float last = -INFINITY;
        for (int t = 0; t < 32; t++) {
            float bv = -INFINITY, bx = 0.f, by = 0.f, bz = 0.f;
            int bo = INT_MAX;
#pragma unroll
            for (int m = 0; m < SLOTS; m++) {
                bool c = (hh[m] > bv) || (hh[m] == bv && ii[m] < bo);
                if (c) { bv = hh[m]; bo = ii[m]; bx = xx[m]; by = yy[m]; bz = zz[m]; }
            }
#pragma unroll
            for (int off = 32; off > 0; off >>= 1) {
                float ov = __shfl_down(bv, off);
                int   oo = __shfl_down(bo, off);
                float ox = __shfl_down(bx, off);
                float oy = __shfl_down(by, off);
                float oz = __shfl_down(bz, off);
                bool c = (ov > bv) || (ov == bv && oo < bo);
                if (c) { bv = ov; bo = oo; bx = ox; by = oy; bz = oz; }
            }
            bv = __shfl(bv, 0); bo = __shfl(bo, 0);
            bx = __shfl(bx, 0); by = __shfl(by, 0); bz = __shfl(bz, 0);
            if (tid == 0) topk[b * 32 + t] = bo;
            last = bv;
#pragma unroll
            for (int m = 0; m < SLOTS; m++) {
                float dx = xx[m] - bx, dy = yy[m] - by, dz = zz[m] - bz;
                if (dx * dx + dy * dy + dz * dz < R2C) hh[m] = -INFINITY;
            }
        }
        if (tid == 0) sh_val = last;
    }
    __syncthreads();
    bool sound = (!overflow) && (C > 0) && (sh_val >= thr);
    if (!sound) {
        // brute-force exact fallback (essentially never taken)
        for (int t = 0; t < 32; t++) {
            float bv = -INFINITY; int bo = INT_MAX;
            for (int n = s + tid; n < e; n += 1024) {
                float x = coords[(size_t)n * 3], y = coords[(size_t)n * 3 + 1], z = coords[(size_t)n * 3 + 2];
                bool sup = false;
                for (int u = 0; u < t; u++) {
                    float dx = x - fbx[u], dy = y - fby[u], dz = z - fbz[u];
                    if (dx * dx + dy * dy + dz * dz < R2C) { sup = true; break; }
                }
                if (!sup) {
                    float h = heat[n];
                    if (h > bv || (h == bv && n < bo)) { bv = h; bo = n; }
                }
            }
#pragma unroll
            for (int off = 32; off > 0; off >>= 1) {
                float ov = __shfl_down(bv, off); int oo = __shfl_down(bo, off);
                if (ov > bv || (ov == bv && oo < bo)) { bv = ov; bo = oo; }
            }
            if ((tid & 63) == 0) { int w = tid >> 6; rv[w] = bv; ri[w] = bo; }
            __syncthreads();
            if (tid == 0) {
                bv = rv[0]; bo = ri[0];
                for (int w = 1; w < 16; w++)
                    if (rv[w] > bv || (rv[w] == bv && ri[w] < bo)) { bv = rv[w]; bo = ri[w]; }
                if (bo == INT_MAX) bo = 0;
                topk[b * 32 + t] = bo;
                fbx[t] = coords[(size_t)bo * 3];
                fby[t] = coords[(size_t)bo * 3 + 1];
                fbz[t] = coords[(size_t)bo * 3 + 2];
            }
            __syncthreads();
        }
    }
}

// ============================ instance prep ===============================
// Vt layout (k-major): Vt[i*352 + k*16 + j], k=0..19 (k==19 = folded bias
// row b1 - ctr.W1pos, paired with a[19]=1); [320..336) = w2; [336] = b2.
__global__ __launch_bounds__(384)
void k_prep(const int* __restrict__ topk, const float* __restrict__ coords,
            const int* __restrict__ bidx, const float* __restrict__ maskf,
            const float* __restrict__ kernf, const float* __restrict__ Wwg,
            const float* __restrict__ bwg, float* __restrict__ Vt,
            float* __restrict__ featw, int* __restrict__ cand_batch) {
    __shared__ float ck[16], cm[16], ctr[3], wrow[337];
    int i = blockIdx.x, tid = threadIdx.x;
    int idx = topk[i];
    if (tid < 16) { ck[tid] = kernf[(size_t)idx * 16 + tid]; cm[tid] = maskf[(size_t)idx * 16 + tid]; }
    else if (tid < 19) ctr[tid - 16] = coords[(size_t)idx * 3 + (tid - 16)];
    else if (tid == 19) cand_batch[i] = bidx[idx];
    __syncthreads();
    for (int c = tid; c < 337; c += 384) {
        float acc = bwg[c];
#pragma unroll
        for (int m = 0; m < 16; m++) acc += ck[m] * Wwg[m * 337 + c];
        wrow[c] = acc;
    }
    __syncthreads();
    for (int t = tid; t < 352; t += 384) {
        float v;
        if (t < 320) {
            int k = t >> 4, j = t & 15;
            if (k < 19) v = wrow[k * 16 + j];
            else {
                v = wrow[304 + j];
#pragma unroll
                for (int p = 0; p < 3; p++) v -= ctr[p] * wrow[(16 + p) * 16 + j];
            }
        } else if (t < 336) v = wrow[320 + (t - 320)];
        else if (t == 336) v = wrow[336];
        else v = 0.f;
        Vt[(size_t)i * 352 + t] = v;
    }
    for (int t = tid; t < 36; t += 384)
        featw[i * 36 + t] = (t < 16) ? ck[t] : (t < 32) ? cm[t - 16] : (t < 35) ? ctr[t - 32] : 0.f;
}

// ============================== mask heads ================================
// One point per thread: a[20] PINNED in VGPRs (asm barrier prevents the
// allocator's remat-reload of maskf/coords seen at VGPR_Count=20 in R4),
// h[16] accumulators, V via uniform pointer -> scalar (SGPR) loads.
__global__ __launch_bounds__(256)
void k_mask(const float* __restrict__ maskf, const float* __restrict__ coords,
            const float* __restrict__ Vt, float* __restrict__ out,
            int N, int ostride) {
    int tid = threadIdx.x;
    int n = blockIdx.x * 256 + tid;
    bool valid = (n < N);
    float a[20];
    if (valid) {
        const float4* fr = (const float4*)(maskf + (size_t)n * 16);
        float4 A = fr[0], B = fr[1], C = fr[2], D = fr[3];
        a[0]=A.x; a[1]=A.y; a[2]=A.z; a[3]=A.w;
        a[4]=B.x; a[5]=B.y; a[6]=B.z; a[7]=B.w;
        a[8]=C.x; a[9]=C.y; a[10]=C.z; a[11]=C.w;
        a[12]=D.x; a[13]=D.y; a[14]=D.z; a[15]=D.w;
        a[16]=coords[(size_t)n*3]; a[17]=coords[(size_t)n*3+1]; a[18]=coords[(size_t)n*3+2];
    } else {
#pragma unroll
        for (int k = 0; k < 19; k++) a[k] = 0.f;
    }
    a[19] = 1.f;
#pragma unroll
    for (int k = 0; k < 20; k++) asm volatile("" : "+v"(a[k]));  // pin in VGPRs
    int ibase = blockIdx.y * 16;
    for (int ii = 0; ii < 16; ii++) {
        const float* __restrict__ V = Vt + (size_t)(ibase + ii) * 352;  // block-uniform -> s_load
        float h[16];
#pragma unroll
        for (int j = 0; j < 16; j++) h[j] = 0.f;
#pragma unroll
        for (int k = 0; k < 20; k++) {
            float ak = a[k];
#pragma unroll
            for (int j = 0; j < 16; j++) h[j] = fmaf(ak, V[k * 16 + j], h[j]);
        }
        float acc = V[336];
#pragma unroll
        for (int j = 0; j < 16; j++) acc = fmaf(fmaxf(h[j], 0.f), V[320 + j], acc);
        if (valid)
            out[(size_t)(ibase + ii) * ostride + n] = 1.f / (1.f + __expf(-acc));
    }
}

// ============================== merge tower ===============================
__global__ __launch_bounds__(256)
void k_merge1(const float* __restrict__ featw, const float* __restrict__ Wg,
              float* __restrict__ Z, double* __restrict__ stats_out) {
    __shared__ float F[128 * 36];
    int tid = threadIdx.x;
    for (int t = tid; t < 128 * 36; t += 256) F[t] = featw[t];
    __syncthreads();
    int id = blockIdx.x * 256 + tid;
    int a = id >> 7, b = id & 127;
    float d[35];
#pragma unroll
    for (int k = 0; k < 35; k++) d[k] = fmaxf(fabsf(F[a * 36 + k] - F[b * 36 + k]), 1e-6f);
    float z[35];
#pragma unroll
    for (int j = 0; j < 35; j++) z[j] = 0.f;
    for (int k = 0; k < 35; k++) {
        float dk = d[k];
        const float* wr = Wg + k * 35;
#pragma unroll
        for (int j = 0; j < 35; j++) z[j] += dk * wr[j];
    }
#pragma unroll
    for (int j = 0; j < 35; j++) {
        float s = z[j], q = z[j] * z[j];
#pragma unroll
        for (int off = 32; off > 0; off >>= 1) { s += __shfl_down(s, off); q += __shfl_down(q, off); }
        if ((tid & 63) == 0) { atomicAdd(&stats_out[j], (double)s); atomicAdd(&stats_out[35 + j], (double)q); }
    }
    float* zr = Z + (size_t)id * 36;
#pragma unroll
    for (int j = 0; j < 35; j++) zr[j] = z[j];
}

__global__ __launch_bounds__(256)
void k_merge_mid(const float* __restrict__ Zin, const float* __restrict__ Wg,
                 float* __restrict__ Zout, const double* __restrict__ stats_in,
                 double* __restrict__ stats_out) {
    __shared__ float nrm[70];
    int tid = threadIdx.x;
    if (tid < 35) {
        double s = stats_in[tid], q = stats_in[35 + tid];
        double m = s * (1.0 / 16384.0);
        double v = q * (1.0 / 16384.0) - m * m;
        nrm[tid] = (float)m; nrm[35 + tid] = (float)rsqrt(v + (double)EPSB);
    }
    __syncthreads();
    int id = blockIdx.x * 256 + tid;
    const float* zi = Zin + (size_t)id * 36;
    float x[35];
#pragma unroll
    for (int k = 0; k < 35; k++) x[k] = fmaxf((zi[k] - nrm[k]) * nrm[35 + k], 0.f);
    float z[35];
#pragma unroll
    for (int j = 0; j < 35; j++) z[j] = 0.f;
    for (int k = 0; k < 35; k++) {
        float dk = x[k];
        const float* wr = Wg + k * 35;
#pragma unroll
        for (int j = 0; j < 35; j++) z[j] += dk * wr[j];
    }
#pragma unroll
    for (int j = 0; j < 35; j++) {
        float s = z[j], q = z[j] * z[j];
#pragma unroll
        for (int off = 32; off > 0; off >>= 1) { s += __shfl_down(s, off); q += __shfl_down(q, off); }
        if ((tid & 63) == 0) { atomicAdd(&stats_out[j], (double)s); atomicAdd(&stats_out[35 + j], (double)q); }
    }
    float* zr = Zout + (size_t)id * 36;
#pragma unroll
    for (int j = 0; j < 35; j++) zr[j] = z[j];
}

__global__ __launch_bounds__(256)
void k_merge_out(const float* __restrict__ Zin, const float* __restrict__ Wout,
                 const float* __restrict__ bout, const double* __restrict__ stats_in,
                 const int* __restrict__ cand_batch, float* __restrict__ out,
                 int N, int ostride) {
    __shared__ float nrm[70];
    __shared__ int cb[128];
    int tid = threadIdx.x;
    if (tid < 35) {
        double s = stats_in[tid], q = stats_in[35 + tid];
        double m = s * (1.0 / 16384.0);
        double v = q * (1.0 / 16384.0) - m * m;
        nrm[tid] = (float)m; nrm[35 + tid] = (float)rsqrt(v + (double)EPSB);
    }
    if (tid < 128) cb[tid] = cand_batch[tid];
    __syncthreads();
    int id = blockIdx.x * 256 + tid;
    int a = id >> 7, b = id & 127;
    const float* zi = Zin + (size_t)id * 36;
    float s = bout[0];
    for (int k = 0; k < 35; k++)
        s += fmaxf((zi[k] - nrm[k]) * nrm[35 + k], 0.f) * Wout[k];
    float v = 1.f / (1.f + __expf(-s));
    if (cb[a] != cb[b]) v = 0.f;
    out[(size_t)a * ostride + N + b] = v;
}

// =============================== launcher =================================
extern "C" void kernel_launch(void* const* d_in, const int* in_sizes, int n_in,
                              void* d_out, int out_size, void* d_ws, size_t ws_size,
                              hipStream_t stream) {
    const float* of     = (const float*)d_in[0];
    const float* coords = (const float*)d_in[1];
    const float* heat   = (const float*)d_in[2];
    const int*   bidx   = (const int*)d_in[3];
    const float* Wm     = (const float*)d_in[4];
    const float* Wm_out = (const float*)d_in[5];
    const float* bm_out = (const float*)d_in[6];
    const float* Wk     = (const float*)d_in[7];
    const float* Wk_out = (const float*)d_in[8];
    const float* bk_out = (const float*)d_in[9];
    const float* Wg     = (const float*)d_in[10];
    const float* Wg_out = (const float*)d_in[11];
    const float* bg_out = (const float*)d_in[12];
    const float* Wwg    = (const float*)d_in[13];
    const float* bwg    = (const float*)d_in[14];
    float* out = (float*)d_out;
    float* ws  = (float*)d_ws;

    int N = in_sizes[0] / 32;          // 100000
    int ostride = N + 128;             // 100128

    float*  maskf = ws + OFF_MASKF;
    float*  kernf = ws + OFF_KERNF;
    double* stats = (double*)(ws + OFF_STATS);
    float*  Vt    = ws + OFF_VT;
    float*  featw = ws + OFF_FEATW;
    float*  mz1   = ws + OFF_MZ1;
    float*  mz2   = ws + OFF_MZ2;
    int*    topk  = (int*)(ws + OFF_INT);
    int*    cand_batch = topk + 128;

    // tower ping-pong buffers live inside d_out (overwritten before epilogue)
    float* bufAm = out;
    float* bufBm = out + (size_t)N * 32;
    float* bufAk = out + (size_t)N * 64;
    float* bufBk = out + (size_t)N * 96;

    dim3 tg2((N + 255) / 256, 2);

    k_nms<<<4, 1024, 0, stream>>>(heat, coords, bidx, N, topk, stats);
    // both towers per launch (blockIdx.y selects); stats offsets: +t*192
    k_tower2<32><<<tg2, 256, 0, stream>>>(of,    of,    Wm,        Wk,        nullptr, nullptr, bufAm, bufAk, nullptr,     stats + 0,  N);
    k_tower2<32><<<tg2, 256, 0, stream>>>(bufAm, bufAk, Wm + 1024, Wk + 1024, nullptr, nullptr, bufBm, bufBk, stats + 0,   stats + 64, N);
    k_tower2<32><<<tg2, 256, 0, stream>>>(bufBm, bufBk, Wm + 2048, Wk + 2048, nullptr, nullptr, bufAm, bufAk, stats + 64,  stats + 128, N);
    k_tower2<16><<<tg2, 256, 0, stream>>>(bufAm, bufAk, Wm_out,    Wk_out,    bm_out,  bk_out,  maskf, kernf, stats + 128, nullptr,    N);

    k_prep<<<128, 384, 0, stream>>>(topk, coords, bidx, maskf, kernf, Wwg, bwg,
                                    Vt, featw, cand_batch);
    k_mask<<<dim3((N + 255) / 256, 8), 256, 0, stream>>>(maskf, coords, Vt, out, N, ostride);

    k_merge1<<<64, 256, 0, stream>>>(featw, Wg, mz1, stats + 384);
    k_merge_mid<<<64, 256, 0, stream>>>(mz1, Wg + 1225, mz2, stats + 384, stats + 454);
    k_merge_mid<<<64, 256, 0, stream>>>(mz2, Wg + 2450, mz1, stats + 454, stats + 524);
    k_merge_out<<<64, 256, 0, stream>>>(mz1, Wg_out, bg_out, stats + 524, cand_batch,
                                        out, N, ostride);
}